// Round 7
// baseline (8434.174 us; speedup 1.0000x reference)
//
#include <hip/hip_runtime.h>

// B=8, T=1024, E=768, H=12.
// Round 11: r8 GEMM structure restored (k-major-B reg staging for scores/Z;
// t_hl transposes removed -- measured net regression). Softmax phase A fused
// into the scores epilogue (per-column (m,s) partials from acc via shfl_xor;
// 16 partials/column = old RC), sm_part+sm_fin2 deleted; sm_norm reduces
// inline. All-heads W pre-split upfront when ws allows (one launch, 85 MB).
// g_fin atomic k-split 24->12. tierA merged final gated on full NC=8 fit.

typedef __bf16 bf16x8 __attribute__((ext_vector_type(8)));
typedef float  f32x4  __attribute__((ext_vector_type(4)));
typedef unsigned short u16;
typedef u16 u16x8 __attribute__((ext_vector_type(8)));
typedef u16 u16x4 __attribute__((ext_vector_type(4)));
typedef unsigned int u32;

#define RC 16   // softmax partials per column (8 mtiles x 2 wave-halves)

__device__ __forceinline__ float bf2f(u16 u) {
    union { u32 i; float f; } x; x.i = ((u32)u) << 16; return x.f;
}
__device__ __forceinline__ u16 f2bf(float f) {
    __bf16 h = (__bf16)f; union { __bf16 b; u16 u; } x; x.b = h; return x.u;
}
__device__ __forceinline__ void split2(float v, u16& h, u16& l) {
    h = f2bf(v); l = f2bf(v - bf2f(h));
}

__device__ __forceinline__ void gl16(const void* g, void* l) {
    __builtin_amdgcn_global_load_lds(
        (const __attribute__((address_space(1))) u32*)g,
        (__attribute__((address_space(3))) u32*)l, 16, 0, 0);
}

// ---------------- 128x128 split-bf16 core ----------------
// A: hi/lo row-major (M x K, lda), staged via global_load_lds w16,
// source k pre-swizzled (conflict-free, verified r4).
// B: BKMAJ=0 -> B^T hi/lo row-major (N x K, ldb), same gl16 path.
//    BKMAJ=1 -> B hi/lo k-major (K x N, ldb), coalesced u16 loads +
//    swizzled ds_write_b128 (r8-proven).
// WIN=1: per-lane A-source clamp to zero page (quirky flat window).
// mode: 0=C fp32 store, 1=hi/lo bf16 store, 2=atomicAdd fp32,
//       3=mode1 + per-column softmax partials (m, s) into part.
template<int BKMAJ, int WIN>
__device__ __forceinline__ void core(
    const u16* __restrict__ Ah, const u16* __restrict__ Al,
    const u16* __restrict__ Bh, const u16* __restrict__ Bl,
    float* __restrict__ C, u16* __restrict__ Ch, u16* __restrict__ Cl,
    int K, int lda, int ldb, int ldc,
    long long aShift, long long aHi, const u16* __restrict__ zp,
    int mClip, int mode, int mtile, int kChunk, int kChunks, int n0,
    float2* __restrict__ part, float pscale, int pz)
{
    __shared__ u16 Ahs[4096], Als[4096], Bhs[4096], Bls[4096]; // 32 KiB

    const int tid = threadIdx.x, lane = tid & 63, w = tid >> 6;
    const int m0 = mtile * 128;
    const int wm = (w & 1) << 6, wn = (w >> 1) << 6;
    const int lr = lane & 15, lq = lane >> 4;
    const int rs = (lr >> 1) & 3;
    const int fro = (lq ^ rs) << 4;            // frag byte offset in row

    // gl16 staging geometry: wave w covers LDS rows w*16..+15 (call 0)
    // and +64 (call 1); lane -> (row, 16B slot). Source k pre-swizzled.
    const int srow = (w << 4) + (lane >> 2);
    const int kk = (((lane & 3) ^ ((srow >> 1) & 3)) << 3);
    const int lds0 = (w << 10), lds1 = lds0 + 4096;

    // k-major B staging (scores / Z)
    const int nB = tid & 127, khB = (tid >> 7) << 4;
    const int rsB = (nB >> 1) & 3;
    const int sB0 = (((khB >> 3) ^ rsB) << 4);
    const int sB1 = ((((khB >> 3) | 1) ^ rsB) << 4);

    f32x4 acc[4][4] = {};
    const int kLen = K / kChunks;
    const int kBeg = kChunk * kLen, kEnd = kBeg + kLen;

    u16 rBh[16], rBl[16];
    auto loadB = [&](int k0) {
        if constexpr (BKMAJ) {
#pragma unroll
            for (int j = 0; j < 16; ++j) {
                long long o = (long long)(k0 + khB + j) * ldb + n0 + nB;
                rBh[j] = Bh[o]; rBl[j] = Bl[o];
            }
        }
    };
    auto stage = [&](int k0) {
        long long o1 = (long long)(m0 + srow) * lda + k0 + kk;
        long long o2 = o1 + (long long)64 * lda;
        const u16 *p1h = Ah + o1, *p1l = Al + o1;
        const u16 *p2h = Ah + o2, *p2l = Al + o2;
        if constexpr (WIN) {
            long long a1 = o1 + aShift, a2 = o2 + aShift;
            bool v1 = (a1 >= 0) && (a1 < aHi);
            bool v2 = (a2 >= 0) && (a2 < aHi);
            p1h = v1 ? Ah + a1 : zp;  p1l = v1 ? Al + a1 : zp;
            p2h = v2 ? Ah + a2 : zp;  p2l = v2 ? Al + a2 : zp;
        }
        gl16(p1h, (char*)Ahs + lds0);  gl16(p2h, (char*)Ahs + lds1);
        gl16(p1l, (char*)Als + lds0);  gl16(p2l, (char*)Als + lds1);
        if constexpr (!BKMAJ) {
            long long b1 = (long long)(n0 + srow) * ldb + k0 + kk;
            long long b2 = b1 + (long long)64 * ldb;
            gl16(Bh + b1, (char*)Bhs + lds0);  gl16(Bh + b2, (char*)Bhs + lds1);
            gl16(Bl + b1, (char*)Bls + lds0);  gl16(Bl + b2, (char*)Bls + lds1);
        }
    };
    auto writeB = [&]() {
        if constexpr (BKMAJ) {
            u16x8 h0, h1, l0, l1;
#pragma unroll
            for (int j = 0; j < 8; ++j) {
                h0[j] = rBh[j]; h1[j] = rBh[j + 8];
                l0[j] = rBl[j]; l1[j] = rBl[j + 8];
            }
            *(u16x8*)((char*)Bhs + nB * 64 + sB0) = h0;
            *(u16x8*)((char*)Bhs + nB * 64 + sB1) = h1;
            *(u16x8*)((char*)Bls + nB * 64 + sB0) = l0;
            *(u16x8*)((char*)Bls + nB * 64 + sB1) = l1;
        }
    };

    loadB(kBeg);
    for (int k0 = kBeg; k0 < kEnd; k0 += 32) {
        stage(k0);                       // async DMA into LDS (A, and B if !BKMAJ)
        writeB();                        // (BKMAJ) prefetched B -> LDS
        __syncthreads();                 // drains vmcnt + lgkmcnt
        if (k0 + 32 < kEnd) loadB(k0 + 32);   // (BKMAJ) prefetch next

        bf16x8 a_h[4], a_l[4];
#pragma unroll
        for (int mi = 0; mi < 4; ++mi) {
            int off = ((wm + (mi << 4) + lr) << 6) + fro;
            a_h[mi] = *(const bf16x8*)((char*)Ahs + off);
            a_l[mi] = *(const bf16x8*)((char*)Als + off);
        }
#pragma unroll
        for (int ni = 0; ni < 4; ++ni) {
            int off = ((wn + (ni << 4) + lr) << 6) + fro;
            bf16x8 b_h = *(const bf16x8*)((char*)Bhs + off);
            bf16x8 b_l = *(const bf16x8*)((char*)Bls + off);
#pragma unroll
            for (int mi = 0; mi < 4; ++mi) {
                acc[mi][ni] = __builtin_amdgcn_mfma_f32_16x16x32_bf16(a_h[mi], b_h, acc[mi][ni], 0, 0, 0);
                acc[mi][ni] = __builtin_amdgcn_mfma_f32_16x16x32_bf16(a_l[mi], b_h, acc[mi][ni], 0, 0, 0);
                acc[mi][ni] = __builtin_amdgcn_mfma_f32_16x16x32_bf16(a_h[mi], b_l, acc[mi][ni], 0, 0, 0);
            }
        }
        __syncthreads();
    }

    // Epilogue: C/D layout col = lane&15, row = (lane>>4)*4 + reg  [m89]
#pragma unroll
    for (int mi = 0; mi < 4; ++mi)
#pragma unroll
        for (int r = 0; r < 4; ++r) {
            int row = m0 + wm + (mi << 4) + (lq << 2) + r;
            if (row < mClip) {
#pragma unroll
                for (int ni = 0; ni < 4; ++ni) {
                    long long off = (long long)row * ldc + n0 + wn + (ni << 4) + lr;
                    float v = acc[mi][ni][r];
                    if (mode == 2)      atomicAdd(&C[off], v);
                    else if (mode == 0) C[off] = v;
                    else { u16 hh, ll; split2(v, hh, ll); Ch[off] = hh; Cl[off] = ll; }
                }
            }
        }

    // mode 3: per-column softmax partials. Wave's 64 rows of column j live
    // in 16 acc values (mi x r) per lane + 4 lanes (lq). Reduce locally,
    // then shfl_xor over lq; lanes lq==0 write part[pz][mtile*2+(wm>>6)][j].
    if (mode == 3) {
#pragma unroll
        for (int ni = 0; ni < 4; ++ni) {
            float mloc = -3.4e38f;
#pragma unroll
            for (int mi = 0; mi < 4; ++mi)
#pragma unroll
                for (int r = 0; r < 4; ++r)
                    mloc = fmaxf(mloc, acc[mi][ni][r] * pscale);
            float sl = 0.f;
#pragma unroll
            for (int mi = 0; mi < 4; ++mi)
#pragma unroll
                for (int r = 0; r < 4; ++r)
                    sl += __expf(acc[mi][ni][r] * pscale - mloc);
#pragma unroll
            for (int off = 16; off < 64; off <<= 1) {
                float mo = __shfl_xor(mloc, off);
                float so = __shfl_xor(sl, off);
                float mn = fmaxf(mloc, mo);
                sl = sl * __expf(mloc - mn) + so * __expf(mo - mn);
                mloc = mn;
            }
            if (lq == 0) {
                int j = n0 + wn + (ni << 4) + lr;
                part[((long long)pz * RC + (mtile << 1) + (wm >> 6)) * 1024 + j]
                    = make_float2(mloc, sl);
            }
        }
    }
}

// Fused QKV: grid (18, M/128); x = n-tile*3 + z (z innermost so the 18
// blocks sharing an A-panel dispatch adjacently across XCDs).
__global__ __launch_bounds__(256, 4)
void g_qkv(const u16* __restrict__ Xh, const u16* __restrict__ Xl,
           const u16* __restrict__ Wth, const u16* __restrict__ Wtl,
           u16* __restrict__ Qh, u16* __restrict__ Ql,
           u16* __restrict__ Kh, u16* __restrict__ Kl,
           u16* __restrict__ Vh, u16* __restrict__ Vl)
{
    const long long EE = 768LL * 768;
    int z  = blockIdx.x % 3;
    int n0 = (blockIdx.x / 3) * 128;
    const u16* bh = Wth + (long long)z * EE;
    const u16* bl = Wtl + (long long)z * EE;
    u16* ch = (z == 0) ? Qh : (z == 1) ? Kh : Vh;
    u16* cl = (z == 0) ? Ql : (z == 1) ? Kl : Vl;
    core<0, 0>(Xh, Xl, bh, bl, nullptr, ch, cl, 768, 768, 768, 768,
               0, 0, nullptr, 1 << 30, 1, blockIdx.y, 0, 1, n0,
               nullptr, 0.f, 0);
}

// k-major-B GEMM (scores: B = K-flat (768,1024), mode 3; Z: B = V, mode 1).
__global__ __launch_bounds__(256, 4)
void g_km(const u16* __restrict__ Ah, const u16* __restrict__ Al,
          const u16* __restrict__ Bh, const u16* __restrict__ Bl,
          u16* __restrict__ Ch, u16* __restrict__ Cl,
          int K, int lda, int ldb, int ldc,
          long long sA, long long sB, long long sC,
          float2* part, float pscale, int mode)
{
    long long z = blockIdx.z;
    core<1, 0>(Ah + z * sA, Al + z * sA, Bh + z * sB, Bl + z * sB,
               nullptr, Ch + z * sC, Cl + z * sC,
               K, lda, ldb, ldc, 0, 0, nullptr, 1 << 30, mode,
               blockIdx.y, 0, 1, blockIdx.x * 128, part, pscale, (int)z);
}

// Merged final projection (tierA): out[b] = reshape(Zall_b,(1024,9216)) @ WO.
__global__ __launch_bounds__(256, 4)
void g_out(const u16* __restrict__ Zh, const u16* __restrict__ Zl,
           const u16* __restrict__ WOth, const u16* __restrict__ WOtl,
           float* __restrict__ C, int kChunks)
{
    const long long ZB = 12LL * 786432;
    long long z = blockIdx.z;
    int mtile = blockIdx.y / kChunks;
    int kc    = blockIdx.y % kChunks;
    core<0, 0>(Zh + z * ZB, Zl + z * ZB, WOth, WOtl, C + z * 786432LL,
               nullptr, nullptr, 9216, 9216, 9216, 768,
               0, 0, nullptr, 1 << 30, 2, mtile, kc, kChunks, blockIdx.x * 128,
               nullptr, 0.f, 0);
}

// Fallback final projection: windowed A (quirky flat reshape), k-split + atomics.
__global__ __launch_bounds__(256, 4)
void g_fin(const u16* __restrict__ Zh, const u16* __restrict__ Zl,
           const u16* __restrict__ WOth, const u16* __restrict__ WOtl,
           float* __restrict__ C, const u16* __restrict__ zp,
           long long aShift, int mClip, int kChunks)
{
    const long long TE_ = 786432;
    long long z = blockIdx.z;
    core<0, 1>(Zh + z * TE_, Zl + z * TE_, WOth, WOtl, C + z * TE_,
               nullptr, nullptr, 9216, 9216, 9216, 768,
               aShift, TE_, zp, mClip, 2, 0, blockIdx.y, kChunks, blockIdx.x * 128,
               nullptr, 0.f, 0);
}

// fp32 -> (hi,lo) bf16, flat.
__global__ void k_split(const float* __restrict__ s, u16* __restrict__ h,
                        u16* __restrict__ l, long long n)
{
    long long i = ((long long)blockIdx.x * blockDim.x + threadIdx.x) * 4;
    long long stride = (long long)gridDim.x * blockDim.x * 4;
    for (; i < n; i += stride) {
        float4 v = *(const float4*)(s + i);
        u16x4 hh, ll;
        u16 h0, l0, h1, l1, h2, l2, h3, l3;
        split2(v.x, h0, l0); split2(v.y, h1, l1);
        split2(v.z, h2, l2); split2(v.w, h3, l3);
        hh[0] = h0; hh[1] = h1; hh[2] = h2; hh[3] = h3;
        ll[0] = l0; ll[1] = l1; ll[2] = l2; ll[3] = l3;
        *(u16x4*)(h + i) = hh;
        *(u16x4*)(l + i) = ll;
    }
}

// fp32 (Ks x Ns) -> transposed (Ns x Ks) hi/lo bf16.
__global__ void k_tsplit(const float* __restrict__ s, u16* __restrict__ dh,
                         u16* __restrict__ dl, int Ks, int Ns)
{
    __shared__ float t[32][33];
    int tx = threadIdx.x & 31, ty = threadIdx.x >> 5;
    int kb = blockIdx.y << 5, nb_ = blockIdx.x << 5;
#pragma unroll
    for (int i = 0; i < 4; ++i)
        t[ty + 8 * i][tx] = s[(long long)(kb + ty + 8 * i) * Ns + nb_ + tx];
    __syncthreads();
#pragma unroll
    for (int i = 0; i < 4; ++i) {
        float v = t[tx][ty + 8 * i];
        long long o = (long long)(nb_ + ty + 8 * i) * Ks + kb + tx;
        u16 hh, ll; split2(v, hh, ll);
        dh[o] = hh; dl[o] = ll;
    }
}

// Per-head W transpose-split (fallback): z selects WQ/WK/WV; dst += z*E*E.
__global__ void k_tsplit3(const float* __restrict__ s0, const float* __restrict__ s1,
                          const float* __restrict__ s2,
                          u16* __restrict__ dh, u16* __restrict__ dl)
{
    const int E = 768; const long long EE = (long long)E * E;
    const float* s = (blockIdx.z == 0) ? s0 : (blockIdx.z == 1) ? s1 : s2;
    u16* h = dh + blockIdx.z * EE;
    u16* l = dl + blockIdx.z * EE;
    __shared__ float t[32][33];
    int tx = threadIdx.x & 31, ty = threadIdx.x >> 5;
    int kb = blockIdx.y << 5, nb_ = blockIdx.x << 5;
#pragma unroll
    for (int i = 0; i < 4; ++i)
        t[ty + 8 * i][tx] = s[(long long)(kb + ty + 8 * i) * E + nb_ + tx];
    __syncthreads();
#pragma unroll
    for (int i = 0; i < 4; ++i) {
        float v = t[tx][ty + 8 * i];
        long long o = (long long)(nb_ + ty + 8 * i) * E + kb + tx;
        u16 hh, ll; split2(v, hh, ll);
        h[o] = hh; l[o] = ll;
    }
}

// All-heads W transpose-split: z = h*3 + w; one launch, grid (24,24,36).
__global__ void k_tsplitA(const float* __restrict__ WQ, const float* __restrict__ WK,
                          const float* __restrict__ WV,
                          u16* __restrict__ dh, u16* __restrict__ dl)
{
    const int E = 768; const long long EE = (long long)E * E;
    int hz = blockIdx.z, hh_ = hz / 3, w = hz % 3;
    const float* s = ((w == 0) ? WQ : (w == 1) ? WK : WV) + (long long)hh_ * EE;
    u16* h = dh + (long long)hz * EE;
    u16* l = dl + (long long)hz * EE;
    __shared__ float t[32][33];
    int tx = threadIdx.x & 31, ty = threadIdx.x >> 5;
    int kb = blockIdx.y << 5, nb_ = blockIdx.x << 5;
#pragma unroll
    for (int i = 0; i < 4; ++i)
        t[ty + 8 * i][tx] = s[(long long)(kb + ty + 8 * i) * E + nb_ + tx];
    __syncthreads();
#pragma unroll
    for (int i = 0; i < 4; ++i) {
        float v = t[tx][ty + 8 * i];
        long long o = (long long)(nb_ + ty + 8 * i) * E + kb + tx;
        u16 hh, ll; split2(v, hh, ll);
        h[o] = hh; l[o] = ll;
    }
}

// Normalize S in place; reduces the RC per-column partials inline.
// grid (T/256, RC, nb); block 256 = 4 row-segs x 64 lanes; lane owns 4 cols.
__global__ __launch_bounds__(256)
void sm_norm(u16* __restrict__ Sh, u16* __restrict__ Sl,
             const float2* __restrict__ part, int T, float scale)
{
    const int lane = threadIdx.x & 63, seg = threadIdx.x >> 6;
    const int j0 = blockIdx.x * 256 + lane * 4;
    const long long base = (long long)blockIdx.z * T * T;
    const int rpc = T / RC, rps = rpc / 4;
    const int r0 = blockIdx.y * rpc + seg * rps;
    float mt[4], inv[4];
#pragma unroll
    for (int c = 0; c < 4; ++c) {
        float m = -3.4e38f, s = 0.f;
#pragma unroll
        for (int q = 0; q < RC; ++q) {
            float2 p = part[((long long)blockIdx.z * RC + q) * 1024 + j0 + c];
            float mn = fmaxf(m, p.x);
            s = s * __expf(m - mn) + p.y * __expf(p.x - mn);
            m = mn;
        }
        mt[c] = m; inv[c] = 1.f / s;
    }
    for (int r = 0; r < rps; ++r) {
        long long o = base + (long long)(r0 + r) * T + j0;
        u16x4 vh = *(const u16x4*)(Sh + o);
        u16x4 vl = *(const u16x4*)(Sl + o);
        u16x4 oh, ol;
#pragma unroll
        for (int c = 0; c < 4; ++c) {
            float v = (bf2f(vh[c]) + bf2f(vl[c])) * scale;
            float p = __expf(v - mt[c]) * inv[c];
            u16 hh, ll; split2(p, hh, ll);
            oh[c] = hh; ol[c] = ll;
        }
        *(u16x4*)(Sh + o) = oh;
        *(u16x4*)(Sl + o) = ol;
    }
}

extern "C" void kernel_launch(void* const* d_in, const int* in_sizes, int n_in,
                              void* d_out, int out_size, void* d_ws, size_t ws_size,
                              hipStream_t stream)
{
    const float* x  = (const float*)d_in[0];   // (B,T,E)
    const float* WQ = (const float*)d_in[1];   // (H,E,E)
    const float* WK = (const float*)d_in[2];
    const float* WV = (const float*)d_in[3];
    const float* WO = (const float*)d_in[4];   // (H*E, E)
    float* out = (float*)d_out;                // (B,T,E)

    const int B = 8, T = 1024, E = 768, H = 12;
    const long long TE = (long long)T * E;     // 786432
    const long long TT = (long long)T * T;     // 1048576
    const long long HE = (long long)H * E;     // 9216
    const long long EE = (long long)E * E;

    // ---- fixed workspace ----
    char* p = (char*)d_ws;
    u16* Xh   = (u16*)p; p += (size_t)B * TE * 2;
    u16* Xl   = (u16*)p; p += (size_t)B * TE * 2;
    u16* WOth = (u16*)p; p += (size_t)E * HE * 2;
    u16* WOtl = (u16*)p; p += (size_t)E * HE * 2;
    u16* zp   = (u16*)p; p += 4096;
    float2* part = (float2*)p; p += (size_t)B * RC * T * sizeof(float2); // 1 MB
    size_t used0 = (size_t)(p - (char*)d_ws);

    const size_t slice = (size_t)(6 * TE + 2 * TT) * 2;  // Q,K,V,S hi/lo: 13.6 MB
    const size_t zsl   = (size_t)12 * TE * 4;            // Zall/batch: 37.7 MB
    const size_t wt12  = (size_t)36 * EE * 2 * 2;        // 85 MB
    const size_t wt1   = (size_t)3 * EE * 2 * 2;         // 7 MB

    long long avail = (long long)ws_size - (long long)used0;
    bool wtAll = false, tierA = false;
    int NC;
    if (avail >= (long long)(wt12 + 8 * (slice + zsl)))      { wtAll = true; tierA = true; NC = 8; }
    else if (avail >= (long long)(wt12 + 8 * slice))         { wtAll = true; NC = 8; }
    else if (avail >= (long long)(wt1 + 8 * slice))          { NC = 8; }
    else { NC = (int)((avail - (long long)wt1) / (long long)slice); if (NC < 1) NC = 1; }

    u16* Wth = (u16*)p;  u16* Wtl;
    if (wtAll) { Wtl = Wth + (size_t)36 * EE; p += wt12; }
    else       { Wtl = Wth + (size_t)3 * EE;  p += wt1;  }
    u16* Qh = (u16*)p; p += (size_t)NC * TE * 2;
    u16* Ql = (u16*)p; p += (size_t)NC * TE * 2;
    u16* Kh = (u16*)p; p += (size_t)NC * TE * 2;
    u16* Kl = (u16*)p; p += (size_t)NC * TE * 2;
    u16* Vh = (u16*)p; p += (size_t)NC * TE * 2;
    u16* Vl = (u16*)p; p += (size_t)NC * TE * 2;
    u16* Sh = (u16*)p; p += (size_t)NC * TT * 2;
    u16* Sl = (u16*)p; p += (size_t)NC * TT * 2;
    u16* Zallh = (u16*)p; if (tierA) p += (size_t)NC * 12 * TE * 2;
    u16* Zalll = (u16*)p;
    u16* Zh = Qh;   // fallback alias: Q dead after scores GEMM
    u16* Zl = Ql;

    hipMemsetAsync(out, 0, (size_t)B * TE * sizeof(float), stream);
    hipMemsetAsync(zp, 0, 4096, stream);

    dim3 blk(256);

    // One-time operand splits.
    k_split<<<2048, blk, 0, stream>>>(x, Xh, Xl, (long long)B * TE);
    k_tsplit<<<dim3(E / 32, (int)HE / 32), blk, 0, stream>>>(WO, WOth, WOtl, (int)HE, E);
    if (wtAll)
        k_tsplitA<<<dim3(24, 24, 36), blk, 0, stream>>>(WQ, WK, WV, Wth, Wtl);

    for (int b0 = 0; b0 < B; b0 += NC) {
        const int nb = (B - b0 < NC) ? (B - b0) : NC;

        for (int h = 0; h < H; ++h) {
            const u16* wh; const u16* wl;
            if (wtAll) { wh = Wth + (size_t)h * 3 * EE; wl = Wtl + (size_t)h * 3 * EE; }
            else {
                k_tsplit3<<<dim3(24, 24, 3), blk, 0, stream>>>(
                    WQ + (size_t)h * EE, WK + (size_t)h * EE, WV + (size_t)h * EE,
                    Wth, Wtl);
                wh = Wth; wl = Wtl;
            }

            // Q/K/V projections: (nb*T x 768) @ (768 x 768), z innermost.
            g_qkv<<<dim3(18, nb * T / 128), blk, 0, stream>>>(
                Xh + (size_t)b0 * TE, Xl + (size_t)b0 * TE, wh, wl,
                Qh, Ql, Kh, Kl, Vh, Vl);

            // Scores: Q (1024x768) @ K-flat (768,1024) k-major; mode 3 writes
            // S hi/lo + per-column softmax partials into part.
            g_km<<<dim3(8, 8, nb), blk, 0, stream>>>(
                Qh, Ql, Kh, Kl, Sh, Sl, 768, 768, 1024, 1024, TE, TE, TT,
                part, 0.03125f, 3);

            // Normalize (reduces RC partials inline).
            sm_norm<<<dim3(T / 256, RC, nb), blk, 0, stream>>>(
                Sh, Sl, part, T, 0.03125f);

            if (tierA) {
                // Z -> Zall[b][h][t][dv] (batch stride 12*TE).
                g_km<<<dim3(6, 8, nb), blk, 0, stream>>>(
                    Sh, Sl, Vh, Vl,
                    Zallh + (size_t)h * TE, Zalll + (size_t)h * TE,
                    1024, 1024, 768, 768, TT, TE, 12 * TE,
                    nullptr, 0.f, 1);
            } else {
                const int i_lo = (int)(((long long)h * TE) / HE);
                const long long aShift = (long long)i_lo * HE - (long long)h * TE;
                g_km<<<dim3(6, 8, nb), blk, 0, stream>>>(
                    Sh, Sl, Vh, Vl, Zh, Zl, 1024, 1024, 768, 768, TT, TE, TE,
                    nullptr, 0.f, 1);
                g_fin<<<dim3(6, 12, nb), blk, 0, stream>>>(
                    Zh, Zl, WOth, WOtl,
                    out + (size_t)b0 * TE + (size_t)i_lo * E, zp,
                    aShift, T - i_lo, 12);
            }
        }

        if (tierA) {
            // Merged final: out[b] = reshape(Zall_b,(1024,9216)) @ WO.
            g_out<<<dim3(6, 8 * 4, nb), blk, 0, stream>>>(
                Zallh, Zalll, WOth, WOtl, out + (size_t)b0 * TE, 4);
        }
    }
}

// Round 8
// 7543.267 us; speedup vs baseline: 1.1181x; 1.1181x over previous
//
#include <hip/hip_runtime.h>

// B=8, T=1024, E=768, H=12.
// Round 12: revert to the measured-good r8 GEMM envelope (runtime mode 0/1/2
// only -- r11's mode-3 fused-softmax epilogue caused scratch spills: 320MB
// WRITE_SIZE, all pipes idle). Kept wins: z-inner g_qkv grid (r9: -7us, -27%
// FETCH), g_fin k-split 24->12, tierA merged final (g_out) + all-heads W
// pre-split, now with NC in {8,4,2} gating tiers.

typedef __bf16 bf16x8 __attribute__((ext_vector_type(8)));
typedef float  f32x4  __attribute__((ext_vector_type(4)));
typedef unsigned short u16;
typedef u16 u16x8 __attribute__((ext_vector_type(8)));
typedef u16 u16x4 __attribute__((ext_vector_type(4)));
typedef unsigned int u32;

#define RC 16   // row-chunks for 3-phase softmax

__device__ __forceinline__ float bf2f(u16 u) {
    union { u32 i; float f; } x; x.i = ((u32)u) << 16; return x.f;
}
__device__ __forceinline__ u16 f2bf(float f) {
    __bf16 h = (__bf16)f; union { __bf16 b; u16 u; } x; x.b = h; return x.u;
}
__device__ __forceinline__ void split2(float v, u16& h, u16& l) {
    h = f2bf(v); l = f2bf(v - bf2f(h));
}

__device__ __forceinline__ void gl16(const void* g, void* l) {
    __builtin_amdgcn_global_load_lds(
        (const __attribute__((address_space(1))) u32*)g,
        (__attribute__((address_space(3))) u32*)l, 16, 0, 0);
}

// ---------------- 128x128 split-bf16 core (r8-exact) ----------------
// A: hi/lo row-major (M x K, lda), staged via global_load_lds w16,
// source k pre-swizzled (conflict-free, verified r4).
// B: BKMAJ=0 -> B^T hi/lo row-major (N x K, ldb), same gl16 path.
//    BKMAJ=1 -> B hi/lo k-major (K x N, ldb), coalesced u16 loads +
//    swizzled ds_write_b128.
// WIN=1: per-lane A-source clamp to zero page (quirky flat window).
// mode: 0=C fp32 store, 1=hi/lo bf16 store, 2=atomicAdd fp32.
template<int BKMAJ, int WIN>
__device__ __forceinline__ void core(
    const u16* __restrict__ Ah, const u16* __restrict__ Al,
    const u16* __restrict__ Bh, const u16* __restrict__ Bl,
    float* __restrict__ C, u16* __restrict__ Ch, u16* __restrict__ Cl,
    int K, int lda, int ldb, int ldc,
    long long aShift, long long aHi, const u16* __restrict__ zp,
    int mClip, int mode, int mtile, int kChunk, int kChunks, int n0)
{
    __shared__ u16 Ahs[4096], Als[4096], Bhs[4096], Bls[4096]; // 32 KiB

    const int tid = threadIdx.x, lane = tid & 63, w = tid >> 6;
    const int m0 = mtile * 128;
    const int wm = (w & 1) << 6, wn = (w >> 1) << 6;
    const int lr = lane & 15, lq = lane >> 4;
    const int rs = (lr >> 1) & 3;
    const int fro = (lq ^ rs) << 4;            // frag byte offset in row

    // gl16 staging geometry: wave w covers LDS rows w*16..+15 (call 0)
    // and +64 (call 1); lane -> (row, 16B slot). Source k pre-swizzled.
    const int srow = (w << 4) + (lane >> 2);
    const int kk = (((lane & 3) ^ ((srow >> 1) & 3)) << 3);
    const int lds0 = (w << 10), lds1 = lds0 + 4096;

    // k-major B staging (scores / Z)
    const int nB = tid & 127, khB = (tid >> 7) << 4;
    const int rsB = (nB >> 1) & 3;
    const int sB0 = (((khB >> 3) ^ rsB) << 4);
    const int sB1 = ((((khB >> 3) | 1) ^ rsB) << 4);

    f32x4 acc[4][4] = {};
    const int kLen = K / kChunks;
    const int kBeg = kChunk * kLen, kEnd = kBeg + kLen;

    u16 rBh[16], rBl[16];
    auto loadB = [&](int k0) {
        if constexpr (BKMAJ) {
#pragma unroll
            for (int j = 0; j < 16; ++j) {
                long long o = (long long)(k0 + khB + j) * ldb + n0 + nB;
                rBh[j] = Bh[o]; rBl[j] = Bl[o];
            }
        }
    };
    auto stage = [&](int k0) {
        long long o1 = (long long)(m0 + srow) * lda + k0 + kk;
        long long o2 = o1 + (long long)64 * lda;
        const u16 *p1h = Ah + o1, *p1l = Al + o1;
        const u16 *p2h = Ah + o2, *p2l = Al + o2;
        if constexpr (WIN) {
            long long a1 = o1 + aShift, a2 = o2 + aShift;
            bool v1 = (a1 >= 0) && (a1 < aHi);
            bool v2 = (a2 >= 0) && (a2 < aHi);
            p1h = v1 ? Ah + a1 : zp;  p1l = v1 ? Al + a1 : zp;
            p2h = v2 ? Ah + a2 : zp;  p2l = v2 ? Al + a2 : zp;
        }
        gl16(p1h, (char*)Ahs + lds0);  gl16(p2h, (char*)Ahs + lds1);
        gl16(p1l, (char*)Als + lds0);  gl16(p2l, (char*)Als + lds1);
        if constexpr (!BKMAJ) {
            long long b1 = (long long)(n0 + srow) * ldb + k0 + kk;
            long long b2 = b1 + (long long)64 * ldb;
            gl16(Bh + b1, (char*)Bhs + lds0);  gl16(Bh + b2, (char*)Bhs + lds1);
            gl16(Bl + b1, (char*)Bls + lds0);  gl16(Bl + b2, (char*)Bls + lds1);
        }
    };
    auto writeB = [&]() {
        if constexpr (BKMAJ) {
            u16x8 h0, h1, l0, l1;
#pragma unroll
            for (int j = 0; j < 8; ++j) {
                h0[j] = rBh[j]; h1[j] = rBh[j + 8];
                l0[j] = rBl[j]; l1[j] = rBl[j + 8];
            }
            *(u16x8*)((char*)Bhs + nB * 64 + sB0) = h0;
            *(u16x8*)((char*)Bhs + nB * 64 + sB1) = h1;
            *(u16x8*)((char*)Bls + nB * 64 + sB0) = l0;
            *(u16x8*)((char*)Bls + nB * 64 + sB1) = l1;
        }
    };

    loadB(kBeg);
    for (int k0 = kBeg; k0 < kEnd; k0 += 32) {
        stage(k0);                       // async DMA into LDS (A, and B if !BKMAJ)
        writeB();                        // (BKMAJ) prefetched B -> LDS
        __syncthreads();                 // drains vmcnt + lgkmcnt
        if (k0 + 32 < kEnd) loadB(k0 + 32);   // (BKMAJ) prefetch next

        bf16x8 a_h[4], a_l[4];
#pragma unroll
        for (int mi = 0; mi < 4; ++mi) {
            int off = ((wm + (mi << 4) + lr) << 6) + fro;
            a_h[mi] = *(const bf16x8*)((char*)Ahs + off);
            a_l[mi] = *(const bf16x8*)((char*)Als + off);
        }
#pragma unroll
        for (int ni = 0; ni < 4; ++ni) {
            int off = ((wn + (ni << 4) + lr) << 6) + fro;
            bf16x8 b_h = *(const bf16x8*)((char*)Bhs + off);
            bf16x8 b_l = *(const bf16x8*)((char*)Bls + off);
#pragma unroll
            for (int mi = 0; mi < 4; ++mi) {
                acc[mi][ni] = __builtin_amdgcn_mfma_f32_16x16x32_bf16(a_h[mi], b_h, acc[mi][ni], 0, 0, 0);
                acc[mi][ni] = __builtin_amdgcn_mfma_f32_16x16x32_bf16(a_l[mi], b_h, acc[mi][ni], 0, 0, 0);
                acc[mi][ni] = __builtin_amdgcn_mfma_f32_16x16x32_bf16(a_h[mi], b_l, acc[mi][ni], 0, 0, 0);
            }
        }
        __syncthreads();
    }

    // Epilogue: C/D layout col = lane&15, row = (lane>>4)*4 + reg  [m89]
#pragma unroll
    for (int mi = 0; mi < 4; ++mi)
#pragma unroll
        for (int r = 0; r < 4; ++r) {
            int row = m0 + wm + (mi << 4) + (lq << 2) + r;
            if (row < mClip) {
#pragma unroll
                for (int ni = 0; ni < 4; ++ni) {
                    long long off = (long long)row * ldc + n0 + wn + (ni << 4) + lr;
                    float v = acc[mi][ni][r];
                    if (mode == 2)      atomicAdd(&C[off], v);
                    else if (mode == 1) { u16 hh, ll; split2(v, hh, ll); Ch[off] = hh; Cl[off] = ll; }
                    else                C[off] = v;
                }
            }
        }
}

// Fused QKV: grid (18, M/128); x = n-tile*3 + z (z innermost so the 18
// blocks sharing an A-panel dispatch adjacently across XCDs). [r9-verified]
__global__ __launch_bounds__(256, 4)
void g_qkv(const u16* __restrict__ Xh, const u16* __restrict__ Xl,
           const u16* __restrict__ Wth, const u16* __restrict__ Wtl,
           u16* __restrict__ Qh, u16* __restrict__ Ql,
           u16* __restrict__ Kh, u16* __restrict__ Kl,
           u16* __restrict__ Vh, u16* __restrict__ Vl)
{
    const long long EE = 768LL * 768;
    int z  = blockIdx.x % 3;
    int n0 = (blockIdx.x / 3) * 128;
    const u16* bh = Wth + (long long)z * EE;
    const u16* bl = Wtl + (long long)z * EE;
    u16* ch = (z == 0) ? Qh : (z == 1) ? Kh : Vh;
    u16* cl = (z == 0) ? Ql : (z == 1) ? Kl : Vl;
    core<0, 0>(Xh, Xl, bh, bl, nullptr, ch, cl, 768, 768, 768, 768,
               0, 0, nullptr, 1 << 30, 1, blockIdx.y, 0, 1, n0);
}

// k-major-B GEMM (scores: B = K-flat (768,1024); Z: B = V). [r8-exact]
__global__ __launch_bounds__(256, 3)
void g_km(const u16* __restrict__ Ah, const u16* __restrict__ Al,
          const u16* __restrict__ Bh, const u16* __restrict__ Bl,
          u16* __restrict__ Ch, u16* __restrict__ Cl,
          int K, int lda, int ldb, int ldc,
          long long sA, long long sB, long long sC)
{
    long long z = blockIdx.z;
    core<1, 0>(Ah + z * sA, Al + z * sA, Bh + z * sB, Bl + z * sB,
               nullptr, Ch + z * sC, Cl + z * sC,
               K, lda, ldb, ldc, 0, 0, nullptr, 1 << 30, 1,
               blockIdx.y, 0, 1, blockIdx.x * 128);
}

// Merged final projection (tierA): out[b] = reshape(Zall_b,(1024,9216)) @ WO.
// grid (6, 8*kChunks, nb); mode 2 (atomic add of k-chunk partials).
__global__ __launch_bounds__(256, 4)
void g_out(const u16* __restrict__ Zh, const u16* __restrict__ Zl,
           const u16* __restrict__ WOth, const u16* __restrict__ WOtl,
           float* __restrict__ C, int kChunks)
{
    const long long ZB = 12LL * 786432;
    long long z = blockIdx.z;
    int mtile = blockIdx.y / kChunks;
    int kc    = blockIdx.y % kChunks;
    core<0, 0>(Zh + z * ZB, Zl + z * ZB, WOth, WOtl, C + z * 786432LL,
               nullptr, nullptr, 9216, 9216, 9216, 768,
               0, 0, nullptr, 1 << 30, 2, mtile, kc, kChunks, blockIdx.x * 128);
}

// Fallback final projection: windowed A (quirky flat reshape), k-split + atomics.
__global__ __launch_bounds__(256, 3)
void g_fin(const u16* __restrict__ Zh, const u16* __restrict__ Zl,
           const u16* __restrict__ WOth, const u16* __restrict__ WOtl,
           float* __restrict__ C, const u16* __restrict__ zp,
           long long aShift, int mClip, int kChunks)
{
    const long long TE_ = 786432;
    long long z = blockIdx.z;
    core<0, 1>(Zh + z * TE_, Zl + z * TE_, WOth, WOtl, C + z * TE_,
               nullptr, nullptr, 9216, 9216, 9216, 768,
               aShift, TE_, zp, mClip, 2, 0, blockIdx.y, kChunks, blockIdx.x * 128);
}

// fp32 -> (hi,lo) bf16, flat.
__global__ void k_split(const float* __restrict__ s, u16* __restrict__ h,
                        u16* __restrict__ l, long long n)
{
    long long i = ((long long)blockIdx.x * blockDim.x + threadIdx.x) * 4;
    long long stride = (long long)gridDim.x * blockDim.x * 4;
    for (; i < n; i += stride) {
        float4 v = *(const float4*)(s + i);
        u16x4 hh, ll;
        u16 h0, l0, h1, l1, h2, l2, h3, l3;
        split2(v.x, h0, l0); split2(v.y, h1, l1);
        split2(v.z, h2, l2); split2(v.w, h3, l3);
        hh[0] = h0; hh[1] = h1; hh[2] = h2; hh[3] = h3;
        ll[0] = l0; ll[1] = l1; ll[2] = l2; ll[3] = l3;
        *(u16x4*)(h + i) = hh;
        *(u16x4*)(l + i) = ll;
    }
}

// fp32 (Ks x Ns) -> transposed (Ns x Ks) hi/lo bf16.
__global__ void k_tsplit(const float* __restrict__ s, u16* __restrict__ dh,
                         u16* __restrict__ dl, int Ks, int Ns)
{
    __shared__ float t[32][33];
    int tx = threadIdx.x & 31, ty = threadIdx.x >> 5;
    int kb = blockIdx.y << 5, nb_ = blockIdx.x << 5;
#pragma unroll
    for (int i = 0; i < 4; ++i)
        t[ty + 8 * i][tx] = s[(long long)(kb + ty + 8 * i) * Ns + nb_ + tx];
    __syncthreads();
#pragma unroll
    for (int i = 0; i < 4; ++i) {
        float v = t[tx][ty + 8 * i];
        long long o = (long long)(nb_ + ty + 8 * i) * Ks + kb + tx;
        u16 hh, ll; split2(v, hh, ll);
        dh[o] = hh; dl[o] = ll;
    }
}

// Per-head W transpose-split (fallback): z selects WQ/WK/WV; dst += z*E*E.
__global__ void k_tsplit3(const float* __restrict__ s0, const float* __restrict__ s1,
                          const float* __restrict__ s2,
                          u16* __restrict__ dh, u16* __restrict__ dl)
{
    const int E = 768; const long long EE = (long long)E * E;
    const float* s = (blockIdx.z == 0) ? s0 : (blockIdx.z == 1) ? s1 : s2;
    u16* h = dh + blockIdx.z * EE;
    u16* l = dl + blockIdx.z * EE;
    __shared__ float t[32][33];
    int tx = threadIdx.x & 31, ty = threadIdx.x >> 5;
    int kb = blockIdx.y << 5, nb_ = blockIdx.x << 5;
#pragma unroll
    for (int i = 0; i < 4; ++i)
        t[ty + 8 * i][tx] = s[(long long)(kb + ty + 8 * i) * E + nb_ + tx];
    __syncthreads();
#pragma unroll
    for (int i = 0; i < 4; ++i) {
        float v = t[tx][ty + 8 * i];
        long long o = (long long)(nb_ + ty + 8 * i) * E + kb + tx;
        u16 hh, ll; split2(v, hh, ll);
        h[o] = hh; l[o] = ll;
    }
}

// All-heads W transpose-split: z = h*3 + w; one launch, grid (24,24,36).
__global__ void k_tsplitA(const float* __restrict__ WQ, const float* __restrict__ WK,
                          const float* __restrict__ WV,
                          u16* __restrict__ dh, u16* __restrict__ dl)
{
    const int E = 768; const long long EE = (long long)E * E;
    int hz = blockIdx.z, hh_ = hz / 3, w = hz % 3;
    const float* s = ((w == 0) ? WQ : (w == 1) ? WK : WV) + (long long)hh_ * EE;
    u16* h = dh + (long long)hz * EE;
    u16* l = dl + (long long)hz * EE;
    __shared__ float t[32][33];
    int tx = threadIdx.x & 31, ty = threadIdx.x >> 5;
    int kb = blockIdx.y << 5, nb_ = blockIdx.x << 5;
#pragma unroll
    for (int i = 0; i < 4; ++i)
        t[ty + 8 * i][tx] = s[(long long)(kb + ty + 8 * i) * E + nb_ + tx];
    __syncthreads();
#pragma unroll
    for (int i = 0; i < 4; ++i) {
        float v = t[tx][ty + 8 * i];
        long long o = (long long)(nb_ + ty + 8 * i) * E + kb + tx;
        u16 hh, ll; split2(v, hh, ll);
        h[o] = hh; l[o] = ll;
    }
}

// ---------------- 3-phase column softmax (query-axis) [r8-exact] --------
__global__ __launch_bounds__(256)
void sm_part(const u16* __restrict__ Sh, const u16* __restrict__ Sl,
             float2* __restrict__ part, int T, float scale)
{
    const int lane = threadIdx.x & 63, seg = threadIdx.x >> 6;
    const int j0 = blockIdx.x * 256 + lane * 4;
    const long long base = (long long)blockIdx.z * T * T;
    const int rpc = T / RC, rps = rpc / 4;
    const int r0 = blockIdx.y * rpc + seg * rps;

    float m[4] = {-3.4e38f, -3.4e38f, -3.4e38f, -3.4e38f};
    float s[4] = {0.f, 0.f, 0.f, 0.f};
    for (int r = 0; r < rps; ++r) {
        long long o = base + (long long)(r0 + r) * T + j0;
        u16x4 vh = *(const u16x4*)(Sh + o);
        u16x4 vl = *(const u16x4*)(Sl + o);
#pragma unroll
        for (int c = 0; c < 4; ++c) {
            float v = (bf2f(vh[c]) + bf2f(vl[c])) * scale;
            float mn = fmaxf(m[c], v);
            s[c] = s[c] * __expf(m[c] - mn) + __expf(v - mn);
            m[c] = mn;
        }
    }
    __shared__ float4 smm[4][64], sss[4][64];
    smm[seg][lane] = make_float4(m[0], m[1], m[2], m[3]);
    sss[seg][lane] = make_float4(s[0], s[1], s[2], s[3]);
    __syncthreads();
    if (seg == 0) {
#pragma unroll
        for (int q = 1; q < 4; ++q) {
            float4 mq4 = smm[q][lane], sq4 = sss[q][lane];
            float mq[4] = {mq4.x, mq4.y, mq4.z, mq4.w};
            float sq[4] = {sq4.x, sq4.y, sq4.z, sq4.w};
#pragma unroll
            for (int c = 0; c < 4; ++c) {
                float mn = fmaxf(m[c], mq[c]);
                s[c] = s[c] * __expf(m[c] - mn) + sq[c] * __expf(mq[c] - mn);
                m[c] = mn;
            }
        }
        long long pb = ((long long)blockIdx.z * RC + blockIdx.y) * T + j0;
#pragma unroll
        for (int c = 0; c < 4; ++c)
            part[pb + c] = make_float2(m[c], s[c]);
    }
}

__global__ __launch_bounds__(256)
void sm_fin2(const float2* __restrict__ part, float2* __restrict__ fin, int T)
{
    int j = blockIdx.x * 256 + threadIdx.x;
    long long pb = (long long)blockIdx.y * RC * T + j;
    float mt = -3.4e38f, st = 0.f;
#pragma unroll
    for (int q = 0; q < RC; ++q) {
        float2 p = part[pb + (long long)q * T];
        float mn = fmaxf(mt, p.x);
        st = st * __expf(mt - mn) + p.y * __expf(p.x - mn);
        mt = mn;
    }
    fin[(long long)blockIdx.y * T + j] = make_float2(mt, 1.f / st);
}

__global__ __launch_bounds__(256)
void sm_norm(u16* __restrict__ Sh, u16* __restrict__ Sl,
             const float2* __restrict__ fin, int T, float scale)
{
    const int lane = threadIdx.x & 63, seg = threadIdx.x >> 6;
    const int j0 = blockIdx.x * 256 + lane * 4;
    const long long base = (long long)blockIdx.z * T * T;
    const int rpc = T / RC, rps = rpc / 4;
    const int r0 = blockIdx.y * rpc + seg * rps;
    float mt[4], inv[4];
#pragma unroll
    for (int c = 0; c < 4; ++c) {
        float2 f = fin[(long long)blockIdx.z * T + j0 + c];
        mt[c] = f.x; inv[c] = f.y;
    }
    for (int r = 0; r < rps; ++r) {
        long long o = base + (long long)(r0 + r) * T + j0;
        u16x4 vh = *(const u16x4*)(Sh + o);
        u16x4 vl = *(const u16x4*)(Sl + o);
        u16x4 oh, ol;
#pragma unroll
        for (int c = 0; c < 4; ++c) {
            float v = (bf2f(vh[c]) + bf2f(vl[c])) * scale;
            float p = __expf(v - mt[c]) * inv[c];
            u16 hh, ll; split2(p, hh, ll);
            oh[c] = hh; ol[c] = ll;
        }
        *(u16x4*)(Sh + o) = oh;
        *(u16x4*)(Sl + o) = ol;
    }
}

extern "C" void kernel_launch(void* const* d_in, const int* in_sizes, int n_in,
                              void* d_out, int out_size, void* d_ws, size_t ws_size,
                              hipStream_t stream)
{
    const float* x  = (const float*)d_in[0];   // (B,T,E)
    const float* WQ = (const float*)d_in[1];   // (H,E,E)
    const float* WK = (const float*)d_in[2];
    const float* WV = (const float*)d_in[3];
    const float* WO = (const float*)d_in[4];   // (H*E, E)
    float* out = (float*)d_out;                // (B,T,E)

    const int B = 8, T = 1024, E = 768, H = 12;
    const long long TE = (long long)T * E;     // 786432
    const long long TT = (long long)T * T;     // 1048576
    const long long HE = (long long)H * E;     // 9216
    const long long EE = (long long)E * E;

    // ---- fixed workspace ----
    char* p = (char*)d_ws;
    u16* Xh   = (u16*)p; p += (size_t)B * TE * 2;
    u16* Xl   = (u16*)p; p += (size_t)B * TE * 2;
    u16* WOth = (u16*)p; p += (size_t)E * HE * 2;
    u16* WOtl = (u16*)p; p += (size_t)E * HE * 2;
    u16* zp   = (u16*)p; p += 4096;
    float2* part = (float2*)p; p += (size_t)B * RC * T * sizeof(float2); // 1 MB
    float2* finb = (float2*)p; p += (size_t)B * T * sizeof(float2);      // 64 KB
    size_t used0 = (size_t)(p - (char*)d_ws);

    const size_t slice = (size_t)(6 * TE + 2 * TT) * 2;  // Q,K,V,S hi/lo: 13.6 MB
    const size_t zsl   = (size_t)12 * TE * 4;            // Zall/batch: 37.7 MB
    const size_t wt12  = (size_t)36 * EE * 2 * 2;        // 85 MB
    const size_t wt1   = (size_t)3 * EE * 2 * 2;         // 7 MB

    long long avail = (long long)ws_size - (long long)used0;
    bool wtAll = false, tierA = false;
    int NC = 0;
    // Prefer tierA (merged final) at the largest NC that fits.
    long long nca = (avail - (long long)wt12) / (long long)(slice + zsl);
    if (nca >= 2) { tierA = true; wtAll = true; NC = (int)(nca > 8 ? 8 : nca); }
    else if (avail >= (long long)(wt12 + 8 * slice)) { wtAll = true; NC = 8; }
    else if (avail >= (long long)(wt1 + 8 * slice))  { NC = 8; }
    else {
        NC = (int)((avail - (long long)wt1) / (long long)slice);
        if (NC < 1) NC = 1;
    }
    if (NC > B) NC = B;

    u16* Wth = (u16*)p;  u16* Wtl;
    if (wtAll) { Wtl = Wth + (size_t)36 * EE; p += wt12; }
    else       { Wtl = Wth + (size_t)3 * EE;  p += wt1;  }
    u16* Qh = (u16*)p; p += (size_t)NC * TE * 2;
    u16* Ql = (u16*)p; p += (size_t)NC * TE * 2;
    u16* Kh = (u16*)p; p += (size_t)NC * TE * 2;
    u16* Kl = (u16*)p; p += (size_t)NC * TE * 2;
    u16* Vh = (u16*)p; p += (size_t)NC * TE * 2;
    u16* Vl = (u16*)p; p += (size_t)NC * TE * 2;
    u16* Sh = (u16*)p; p += (size_t)NC * TT * 2;
    u16* Sl = (u16*)p; p += (size_t)NC * TT * 2;
    u16* Zallh = (u16*)p; if (tierA) p += (size_t)NC * 12 * TE * 2;
    u16* Zalll = (u16*)p;
    u16* Zh = Qh;   // fallback alias: Q dead after scores GEMM
    u16* Zl = Ql;

    hipMemsetAsync(out, 0, (size_t)B * TE * sizeof(float), stream);
    hipMemsetAsync(zp, 0, 4096, stream);

    dim3 blk(256);

    // One-time operand splits.
    k_split<<<2048, blk, 0, stream>>>(x, Xh, Xl, (long long)B * TE);
    k_tsplit<<<dim3(E / 32, (int)HE / 32), blk, 0, stream>>>(WO, WOth, WOtl, (int)HE, E);
    if (wtAll)
        k_tsplitA<<<dim3(24, 24, 36), blk, 0, stream>>>(WQ, WK, WV, Wth, Wtl);

    for (int b0 = 0; b0 < B; b0 += NC) {
        const int nb = (B - b0 < NC) ? (B - b0) : NC;

        for (int h = 0; h < H; ++h) {
            const u16* wh; const u16* wl;
            if (wtAll) { wh = Wth + (size_t)h * 3 * EE; wl = Wtl + (size_t)h * 3 * EE; }
            else {
                k_tsplit3<<<dim3(24, 24, 3), blk, 0, stream>>>(
                    WQ + (size_t)h * EE, WK + (size_t)h * EE, WV + (size_t)h * EE,
                    Wth, Wtl);
                wh = Wth; wl = Wtl;
            }

            // Q/K/V projections: (nb*T x 768) @ (768 x 768), z innermost.
            g_qkv<<<dim3(18, nb * T / 128), blk, 0, stream>>>(
                Xh + (size_t)b0 * TE, Xl + (size_t)b0 * TE, wh, wl,
                Qh, Ql, Kh, Kl, Vh, Vl);

            // Scores: Q (1024x768) @ K-flat (768,1024) k-major, ldb=T.
            g_km<<<dim3(8, 8, nb), blk, 0, stream>>>(
                Qh, Ql, Kh, Kl, Sh, Sl, 768, 768, 1024, 1024, TE, TE, TT);

            // Softmax over query axis, 1/sqrt(T) pre-scale, 3-phase.
            sm_part<<<dim3(T / 256, RC, nb), blk, 0, stream>>>(Sh, Sl, part, T, 0.03125f);
            sm_fin2<<<dim3(T / 256, nb), blk, 0, stream>>>(part, finb, T);
            sm_norm<<<dim3(T / 256, RC, nb), blk, 0, stream>>>(Sh, Sl, finb, T, 0.03125f);

            if (tierA) {
                // Z -> Zall[b][h][t][dv] (batch stride 12*TE).
                g_km<<<dim3(6, 8, nb), blk, 0, stream>>>(
                    Sh, Sl, Vh, Vl,
                    Zallh + (size_t)h * TE, Zalll + (size_t)h * TE,
                    1024, 1024, 768, 768, TT, TE, 12 * TE);
            } else {
                const int i_lo = (int)(((long long)h * TE) / HE);
                const long long aShift = (long long)i_lo * HE - (long long)h * TE;
                g_km<<<dim3(6, 8, nb), blk, 0, stream>>>(
                    Sh, Sl, Vh, Vl, Zh, Zl, 1024, 1024, 768, 768, TT, TE, TE);
                g_fin<<<dim3(6, 12, nb), blk, 0, stream>>>(
                    Zh, Zl, WOth, WOtl,
                    out + (size_t)b0 * TE + (size_t)i_lo * E, zp,
                    aShift, T - i_lo, 12);
            }
        }

        if (tierA) {
            // Merged final: out[b] = reshape(Zall_b,(1024,9216)) @ WO.
            g_out<<<dim3(6, 8 * 4, nb), blk, 0, stream>>>(
                Zallh, Zalll, WOth, WOtl, out + (size_t)b0 * TE, 4);
        }
    }
}

// Round 9
// 4160.359 us; speedup vs baseline: 2.0273x; 1.8131x over previous
//
#include <hip/hip_runtime.h>

// B=8, T=1024, E=768, H=12.
// Round 13: exact reproduction of the r8 measured-good config (4289 us):
// r8 core / g_km / g_fin(kChunks=24) / 3-phase softmax, NC=8 slice math.
// Only dispatch-verified deltas on top: g_qkv z-inner grid lb(256,4)
// (115->108us, FETCH -27%, r5 counters) and one-launch all-heads W pre-split
// (cold path) when it fits beside NC=8. tierA (merged final) strictly gated
// on NC==8 fit (~495MB) -- r12's NC=2 tierA collapsed every grid 4x.

typedef __bf16 bf16x8 __attribute__((ext_vector_type(8)));
typedef float  f32x4  __attribute__((ext_vector_type(4)));
typedef unsigned short u16;
typedef u16 u16x8 __attribute__((ext_vector_type(8)));
typedef u16 u16x4 __attribute__((ext_vector_type(4)));
typedef unsigned int u32;

#define RC 16   // row-chunks for 3-phase softmax

__device__ __forceinline__ float bf2f(u16 u) {
    union { u32 i; float f; } x; x.i = ((u32)u) << 16; return x.f;
}
__device__ __forceinline__ u16 f2bf(float f) {
    __bf16 h = (__bf16)f; union { __bf16 b; u16 u; } x; x.b = h; return x.u;
}
__device__ __forceinline__ void split2(float v, u16& h, u16& l) {
    h = f2bf(v); l = f2bf(v - bf2f(h));
}

__device__ __forceinline__ void gl16(const void* g, void* l) {
    __builtin_amdgcn_global_load_lds(
        (const __attribute__((address_space(1))) u32*)g,
        (__attribute__((address_space(3))) u32*)l, 16, 0, 0);
}

// ---------------- 128x128 split-bf16 core (r8-exact) ----------------
// A: hi/lo row-major (M x K, lda), staged via global_load_lds w16,
// source k pre-swizzled (conflict-free, verified r4).
// B: BKMAJ=0 -> B^T hi/lo row-major (N x K, ldb), same gl16 path.
//    BKMAJ=1 -> B hi/lo k-major (K x N, ldb), coalesced u16 loads +
//    swizzled ds_write_b128.
// WIN=1: per-lane A-source clamp to zero page (quirky flat window).
// mode: 0=C fp32 store, 1=hi/lo bf16 store, 2=atomicAdd fp32.
template<int BKMAJ, int WIN>
__device__ __forceinline__ void core(
    const u16* __restrict__ Ah, const u16* __restrict__ Al,
    const u16* __restrict__ Bh, const u16* __restrict__ Bl,
    float* __restrict__ C, u16* __restrict__ Ch, u16* __restrict__ Cl,
    int K, int lda, int ldb, int ldc,
    long long aShift, long long aHi, const u16* __restrict__ zp,
    int mClip, int mode, int mtile, int kChunk, int kChunks, int n0)
{
    __shared__ u16 Ahs[4096], Als[4096], Bhs[4096], Bls[4096]; // 32 KiB

    const int tid = threadIdx.x, lane = tid & 63, w = tid >> 6;
    const int m0 = mtile * 128;
    const int wm = (w & 1) << 6, wn = (w >> 1) << 6;
    const int lr = lane & 15, lq = lane >> 4;
    const int rs = (lr >> 1) & 3;
    const int fro = (lq ^ rs) << 4;            // frag byte offset in row

    // gl16 staging geometry: wave w covers LDS rows w*16..+15 (call 0)
    // and +64 (call 1); lane -> (row, 16B slot). Source k pre-swizzled.
    const int srow = (w << 4) + (lane >> 2);
    const int kk = (((lane & 3) ^ ((srow >> 1) & 3)) << 3);
    const int lds0 = (w << 10), lds1 = lds0 + 4096;

    // k-major B staging (scores / Z)
    const int nB = tid & 127, khB = (tid >> 7) << 4;
    const int rsB = (nB >> 1) & 3;
    const int sB0 = (((khB >> 3) ^ rsB) << 4);
    const int sB1 = ((((khB >> 3) | 1) ^ rsB) << 4);

    f32x4 acc[4][4] = {};
    const int kLen = K / kChunks;
    const int kBeg = kChunk * kLen, kEnd = kBeg + kLen;

    u16 rBh[16], rBl[16];
    auto loadB = [&](int k0) {
        if constexpr (BKMAJ) {
#pragma unroll
            for (int j = 0; j < 16; ++j) {
                long long o = (long long)(k0 + khB + j) * ldb + n0 + nB;
                rBh[j] = Bh[o]; rBl[j] = Bl[o];
            }
        }
    };
    auto stage = [&](int k0) {
        long long o1 = (long long)(m0 + srow) * lda + k0 + kk;
        long long o2 = o1 + (long long)64 * lda;
        const u16 *p1h = Ah + o1, *p1l = Al + o1;
        const u16 *p2h = Ah + o2, *p2l = Al + o2;
        if constexpr (WIN) {
            long long a1 = o1 + aShift, a2 = o2 + aShift;
            bool v1 = (a1 >= 0) && (a1 < aHi);
            bool v2 = (a2 >= 0) && (a2 < aHi);
            p1h = v1 ? Ah + a1 : zp;  p1l = v1 ? Al + a1 : zp;
            p2h = v2 ? Ah + a2 : zp;  p2l = v2 ? Al + a2 : zp;
        }
        gl16(p1h, (char*)Ahs + lds0);  gl16(p2h, (char*)Ahs + lds1);
        gl16(p1l, (char*)Als + lds0);  gl16(p2l, (char*)Als + lds1);
        if constexpr (!BKMAJ) {
            long long b1 = (long long)(n0 + srow) * ldb + k0 + kk;
            long long b2 = b1 + (long long)64 * ldb;
            gl16(Bh + b1, (char*)Bhs + lds0);  gl16(Bh + b2, (char*)Bhs + lds1);
            gl16(Bl + b1, (char*)Bls + lds0);  gl16(Bl + b2, (char*)Bls + lds1);
        }
    };
    auto writeB = [&]() {
        if constexpr (BKMAJ) {
            u16x8 h0, h1, l0, l1;
#pragma unroll
            for (int j = 0; j < 8; ++j) {
                h0[j] = rBh[j]; h1[j] = rBh[j + 8];
                l0[j] = rBl[j]; l1[j] = rBl[j + 8];
            }
            *(u16x8*)((char*)Bhs + nB * 64 + sB0) = h0;
            *(u16x8*)((char*)Bhs + nB * 64 + sB1) = h1;
            *(u16x8*)((char*)Bls + nB * 64 + sB0) = l0;
            *(u16x8*)((char*)Bls + nB * 64 + sB1) = l1;
        }
    };

    loadB(kBeg);
    for (int k0 = kBeg; k0 < kEnd; k0 += 32) {
        stage(k0);                       // async DMA into LDS (A, and B if !BKMAJ)
        writeB();                        // (BKMAJ) prefetched B -> LDS
        __syncthreads();                 // drains vmcnt + lgkmcnt
        if (k0 + 32 < kEnd) loadB(k0 + 32);   // (BKMAJ) prefetch next

        bf16x8 a_h[4], a_l[4];
#pragma unroll
        for (int mi = 0; mi < 4; ++mi) {
            int off = ((wm + (mi << 4) + lr) << 6) + fro;
            a_h[mi] = *(const bf16x8*)((char*)Ahs + off);
            a_l[mi] = *(const bf16x8*)((char*)Als + off);
        }
#pragma unroll
        for (int ni = 0; ni < 4; ++ni) {
            int off = ((wn + (ni << 4) + lr) << 6) + fro;
            bf16x8 b_h = *(const bf16x8*)((char*)Bhs + off);
            bf16x8 b_l = *(const bf16x8*)((char*)Bls + off);
#pragma unroll
            for (int mi = 0; mi < 4; ++mi) {
                acc[mi][ni] = __builtin_amdgcn_mfma_f32_16x16x32_bf16(a_h[mi], b_h, acc[mi][ni], 0, 0, 0);
                acc[mi][ni] = __builtin_amdgcn_mfma_f32_16x16x32_bf16(a_l[mi], b_h, acc[mi][ni], 0, 0, 0);
                acc[mi][ni] = __builtin_amdgcn_mfma_f32_16x16x32_bf16(a_h[mi], b_l, acc[mi][ni], 0, 0, 0);
            }
        }
        __syncthreads();
    }

    // Epilogue: C/D layout col = lane&15, row = (lane>>4)*4 + reg  [m89]
#pragma unroll
    for (int mi = 0; mi < 4; ++mi)
#pragma unroll
        for (int r = 0; r < 4; ++r) {
            int row = m0 + wm + (mi << 4) + (lq << 2) + r;
            if (row < mClip) {
#pragma unroll
                for (int ni = 0; ni < 4; ++ni) {
                    long long off = (long long)row * ldc + n0 + wn + (ni << 4) + lr;
                    float v = acc[mi][ni][r];
                    if (mode == 2)      atomicAdd(&C[off], v);
                    else if (mode == 1) { u16 hh, ll; split2(v, hh, ll); Ch[off] = hh; Cl[off] = ll; }
                    else                C[off] = v;
                }
            }
        }
}

// Fused QKV: grid (18, M/128); x = n-tile*3 + z (z innermost so the 18
// blocks sharing an A-panel dispatch adjacently). [r5-counter-verified]
__global__ __launch_bounds__(256, 4)
void g_qkv(const u16* __restrict__ Xh, const u16* __restrict__ Xl,
           const u16* __restrict__ Wth, const u16* __restrict__ Wtl,
           u16* __restrict__ Qh, u16* __restrict__ Ql,
           u16* __restrict__ Kh, u16* __restrict__ Kl,
           u16* __restrict__ Vh, u16* __restrict__ Vl)
{
    const long long EE = 768LL * 768;
    int z  = blockIdx.x % 3;
    int n0 = (blockIdx.x / 3) * 128;
    const u16* bh = Wth + (long long)z * EE;
    const u16* bl = Wtl + (long long)z * EE;
    u16* ch = (z == 0) ? Qh : (z == 1) ? Kh : Vh;
    u16* cl = (z == 0) ? Ql : (z == 1) ? Kl : Vl;
    core<0, 0>(Xh, Xl, bh, bl, nullptr, ch, cl, 768, 768, 768, 768,
               0, 0, nullptr, 1 << 30, 1, blockIdx.y, 0, 1, n0);
}

// k-major-B GEMM (scores: B = K-flat (768,1024); Z: B = V). [r8-exact]
__global__ __launch_bounds__(256, 3)
void g_km(const u16* __restrict__ Ah, const u16* __restrict__ Al,
          const u16* __restrict__ Bh, const u16* __restrict__ Bl,
          u16* __restrict__ Ch, u16* __restrict__ Cl,
          int K, int lda, int ldb, int ldc,
          long long sA, long long sB, long long sC)
{
    long long z = blockIdx.z;
    core<1, 0>(Ah + z * sA, Al + z * sA, Bh + z * sB, Bl + z * sB,
               nullptr, Ch + z * sC, Cl + z * sC,
               K, lda, ldb, ldc, 0, 0, nullptr, 1 << 30, 1,
               blockIdx.y, 0, 1, blockIdx.x * 128);
}

// Merged final projection (tierA, NC==8 only): out[b] = Zall_b(1024,9216)@WO.
__global__ __launch_bounds__(256, 3)
void g_out(const u16* __restrict__ Zh, const u16* __restrict__ Zl,
           const u16* __restrict__ WOth, const u16* __restrict__ WOtl,
           float* __restrict__ C, int kChunks)
{
    const long long ZB = 12LL * 786432;
    long long z = blockIdx.z;
    int mtile = blockIdx.y / kChunks;
    int kc    = blockIdx.y % kChunks;
    core<0, 0>(Zh + z * ZB, Zl + z * ZB, WOth, WOtl, C + z * 786432LL,
               nullptr, nullptr, 9216, 9216, 9216, 768,
               0, 0, nullptr, 1 << 30, 2, mtile, kc, kChunks, blockIdx.x * 128);
}

// Final projection: windowed A (quirky flat reshape), k-split + atomics. [r8]
__global__ __launch_bounds__(256, 3)
void g_fin(const u16* __restrict__ Zh, const u16* __restrict__ Zl,
           const u16* __restrict__ WOth, const u16* __restrict__ WOtl,
           float* __restrict__ C, const u16* __restrict__ zp,
           long long aShift, int mClip, int kChunks)
{
    const long long TE_ = 786432;
    long long z = blockIdx.z;
    core<0, 1>(Zh + z * TE_, Zl + z * TE_, WOth, WOtl, C + z * TE_,
               nullptr, nullptr, 9216, 9216, 9216, 768,
               aShift, TE_, zp, mClip, 2, 0, blockIdx.y, kChunks, blockIdx.x * 128);
}

// fp32 -> (hi,lo) bf16, flat.
__global__ void k_split(const float* __restrict__ s, u16* __restrict__ h,
                        u16* __restrict__ l, long long n)
{
    long long i = ((long long)blockIdx.x * blockDim.x + threadIdx.x) * 4;
    long long stride = (long long)gridDim.x * blockDim.x * 4;
    for (; i < n; i += stride) {
        float4 v = *(const float4*)(s + i);
        u16x4 hh, ll;
        u16 h0, l0, h1, l1, h2, l2, h3, l3;
        split2(v.x, h0, l0); split2(v.y, h1, l1);
        split2(v.z, h2, l2); split2(v.w, h3, l3);
        hh[0] = h0; hh[1] = h1; hh[2] = h2; hh[3] = h3;
        ll[0] = l0; ll[1] = l1; ll[2] = l2; ll[3] = l3;
        *(u16x4*)(h + i) = hh;
        *(u16x4*)(l + i) = ll;
    }
}

// fp32 (Ks x Ns) -> transposed (Ns x Ks) hi/lo bf16.
__global__ void k_tsplit(const float* __restrict__ s, u16* __restrict__ dh,
                         u16* __restrict__ dl, int Ks, int Ns)
{
    __shared__ float t[32][33];
    int tx = threadIdx.x & 31, ty = threadIdx.x >> 5;
    int kb = blockIdx.y << 5, nb_ = blockIdx.x << 5;
#pragma unroll
    for (int i = 0; i < 4; ++i)
        t[ty + 8 * i][tx] = s[(long long)(kb + ty + 8 * i) * Ns + nb_ + tx];
    __syncthreads();
#pragma unroll
    for (int i = 0; i < 4; ++i) {
        float v = t[tx][ty + 8 * i];
        long long o = (long long)(nb_ + ty + 8 * i) * Ks + kb + tx;
        u16 hh, ll; split2(v, hh, ll);
        dh[o] = hh; dl[o] = ll;
    }
}

// Per-head W transpose-split (fallback): z selects WQ/WK/WV; dst += z*E*E.
__global__ void k_tsplit3(const float* __restrict__ s0, const float* __restrict__ s1,
                          const float* __restrict__ s2,
                          u16* __restrict__ dh, u16* __restrict__ dl)
{
    const int E = 768; const long long EE = (long long)E * E;
    const float* s = (blockIdx.z == 0) ? s0 : (blockIdx.z == 1) ? s1 : s2;
    u16* h = dh + blockIdx.z * EE;
    u16* l = dl + blockIdx.z * EE;
    __shared__ float t[32][33];
    int tx = threadIdx.x & 31, ty = threadIdx.x >> 5;
    int kb = blockIdx.y << 5, nb_ = blockIdx.x << 5;
#pragma unroll
    for (int i = 0; i < 4; ++i)
        t[ty + 8 * i][tx] = s[(long long)(kb + ty + 8 * i) * E + nb_ + tx];
    __syncthreads();
#pragma unroll
    for (int i = 0; i < 4; ++i) {
        float v = t[tx][ty + 8 * i];
        long long o = (long long)(nb_ + ty + 8 * i) * E + kb + tx;
        u16 hh, ll; split2(v, hh, ll);
        h[o] = hh; l[o] = ll;
    }
}

// All-heads W transpose-split (cold path): z = h*3 + w; one launch.
__global__ void k_tsplitA(const float* __restrict__ WQ, const float* __restrict__ WK,
                          const float* __restrict__ WV,
                          u16* __restrict__ dh, u16* __restrict__ dl)
{
    const int E = 768; const long long EE = (long long)E * E;
    int hz = blockIdx.z, hh_ = hz / 3, w = hz % 3;
    const float* s = ((w == 0) ? WQ : (w == 1) ? WK : WV) + (long long)hh_ * EE;
    u16* h = dh + (long long)hz * EE;
    u16* l = dl + (long long)hz * EE;
    __shared__ float t[32][33];
    int tx = threadIdx.x & 31, ty = threadIdx.x >> 5;
    int kb = blockIdx.y << 5, nb_ = blockIdx.x << 5;
#pragma unroll
    for (int i = 0; i < 4; ++i)
        t[ty + 8 * i][tx] = s[(long long)(kb + ty + 8 * i) * E + nb_ + tx];
    __syncthreads();
#pragma unroll
    for (int i = 0; i < 4; ++i) {
        float v = t[tx][ty + 8 * i];
        long long o = (long long)(nb_ + ty + 8 * i) * E + kb + tx;
        u16 hh, ll; split2(v, hh, ll);
        h[o] = hh; l[o] = ll;
    }
}

// ---------------- 3-phase column softmax (query-axis) [r8-exact] --------
__global__ __launch_bounds__(256)
void sm_part(const u16* __restrict__ Sh, const u16* __restrict__ Sl,
             float2* __restrict__ part, int T, float scale)
{
    const int lane = threadIdx.x & 63, seg = threadIdx.x >> 6;
    const int j0 = blockIdx.x * 256 + lane * 4;
    const long long base = (long long)blockIdx.z * T * T;
    const int rpc = T / RC, rps = rpc / 4;
    const int r0 = blockIdx.y * rpc + seg * rps;

    float m[4] = {-3.4e38f, -3.4e38f, -3.4e38f, -3.4e38f};
    float s[4] = {0.f, 0.f, 0.f, 0.f};
    for (int r = 0; r < rps; ++r) {
        long long o = base + (long long)(r0 + r) * T + j0;
        u16x4 vh = *(const u16x4*)(Sh + o);
        u16x4 vl = *(const u16x4*)(Sl + o);
#pragma unroll
        for (int c = 0; c < 4; ++c) {
            float v = (bf2f(vh[c]) + bf2f(vl[c])) * scale;
            float mn = fmaxf(m[c], v);
            s[c] = s[c] * __expf(m[c] - mn) + __expf(v - mn);
            m[c] = mn;
        }
    }
    __shared__ float4 smm[4][64], sss[4][64];
    smm[seg][lane] = make_float4(m[0], m[1], m[2], m[3]);
    sss[seg][lane] = make_float4(s[0], s[1], s[2], s[3]);
    __syncthreads();
    if (seg == 0) {
#pragma unroll
        for (int q = 1; q < 4; ++q) {
            float4 mq4 = smm[q][lane], sq4 = sss[q][lane];
            float mq[4] = {mq4.x, mq4.y, mq4.z, mq4.w};
            float sq[4] = {sq4.x, sq4.y, sq4.z, sq4.w};
#pragma unroll
            for (int c = 0; c < 4; ++c) {
                float mn = fmaxf(m[c], mq[c]);
                s[c] = s[c] * __expf(m[c] - mn) + sq[c] * __expf(mq[c] - mn);
                m[c] = mn;
            }
        }
        long long pb = ((long long)blockIdx.z * RC + blockIdx.y) * T + j0;
#pragma unroll
        for (int c = 0; c < 4; ++c)
            part[pb + c] = make_float2(m[c], s[c]);
    }
}

__global__ __launch_bounds__(256)
void sm_fin2(const float2* __restrict__ part, float2* __restrict__ fin, int T)
{
    int j = blockIdx.x * 256 + threadIdx.x;
    long long pb = (long long)blockIdx.y * RC * T + j;
    float mt = -3.4e38f, st = 0.f;
#pragma unroll
    for (int q = 0; q < RC; ++q) {
        float2 p = part[pb + (long long)q * T];
        float mn = fmaxf(mt, p.x);
        st = st * __expf(mt - mn) + p.y * __expf(p.x - mn);
        mt = mn;
    }
    fin[(long long)blockIdx.y * T + j] = make_float2(mt, 1.f / st);
}

__global__ __launch_bounds__(256)
void sm_norm(u16* __restrict__ Sh, u16* __restrict__ Sl,
             const float2* __restrict__ fin, int T, float scale)
{
    const int lane = threadIdx.x & 63, seg = threadIdx.x >> 6;
    const int j0 = blockIdx.x * 256 + lane * 4;
    const long long base = (long long)blockIdx.z * T * T;
    const int rpc = T / RC, rps = rpc / 4;
    const int r0 = blockIdx.y * rpc + seg * rps;
    float mt[4], inv[4];
#pragma unroll
    for (int c = 0; c < 4; ++c) {
        float2 f = fin[(long long)blockIdx.z * T + j0 + c];
        mt[c] = f.x; inv[c] = f.y;
    }
    for (int r = 0; r < rps; ++r) {
        long long o = base + (long long)(r0 + r) * T + j0;
        u16x4 vh = *(const u16x4*)(Sh + o);
        u16x4 vl = *(const u16x4*)(Sl + o);
        u16x4 oh, ol;
#pragma unroll
        for (int c = 0; c < 4; ++c) {
            float v = (bf2f(vh[c]) + bf2f(vl[c])) * scale;
            float p = __expf(v - mt[c]) * inv[c];
            u16 hh, ll; split2(p, hh, ll);
            oh[c] = hh; ol[c] = ll;
        }
        *(u16x4*)(Sh + o) = oh;
        *(u16x4*)(Sl + o) = ol;
    }
}

extern "C" void kernel_launch(void* const* d_in, const int* in_sizes, int n_in,
                              void* d_out, int out_size, void* d_ws, size_t ws_size,
                              hipStream_t stream)
{
    const float* x  = (const float*)d_in[0];   // (B,T,E)
    const float* WQ = (const float*)d_in[1];   // (H,E,E)
    const float* WK = (const float*)d_in[2];
    const float* WV = (const float*)d_in[3];
    const float* WO = (const float*)d_in[4];   // (H*E, E)
    float* out = (float*)d_out;                // (B,T,E)

    const int B = 8, T = 1024, E = 768, H = 12;
    const long long TE = (long long)T * E;     // 786432
    const long long TT = (long long)T * T;     // 1048576
    const long long HE = (long long)H * E;     // 9216
    const long long EE = (long long)E * E;

    // ---- fixed workspace (r8 layout) ----
    char* p = (char*)d_ws;
    u16* Xh   = (u16*)p; p += (size_t)B * TE * 2;
    u16* Xl   = (u16*)p; p += (size_t)B * TE * 2;
    u16* WOth = (u16*)p; p += (size_t)E * HE * 2;
    u16* WOtl = (u16*)p; p += (size_t)E * HE * 2;
    u16* zp   = (u16*)p; p += 4096;
    float2* part = (float2*)p; p += (size_t)B * RC * T * sizeof(float2); // 1 MB
    float2* finb = (float2*)p; p += (size_t)B * T * sizeof(float2);      // 64 KB
    size_t used0 = (size_t)(p - (char*)d_ws);

    const size_t slice = (size_t)(6 * TE + 2 * TT) * 2;  // Q,K,V,S hi/lo: 13.6 MB
    const size_t zsl   = (size_t)12 * TE * 4;            // Zall/batch: 37.7 MB
    const size_t wt12  = (size_t)36 * EE * 2 * 2;        // 85 MB
    const size_t wt1   = (size_t)3 * EE * 2 * 2;         // 7 MB

    long long avail = (long long)ws_size - (long long)used0;

    // tierA strictly requires the FULL NC=8 configuration (r12 lesson:
    // tierA at small NC collapses every grid -> 1.76x regression).
    const bool tierA = avail >= (long long)(wt12 + 8 * (slice + zsl));
    const bool wtAll = tierA || avail >= (long long)(wt12 + 8 * slice);

    // NC exactly as r8: largest chunk the slice budget allows, cap 8.
    long long wsliceF = avail - (long long)(wtAll ? wt12 : wt1);
    int NC = (int)(wsliceF / (long long)slice);
    if (NC < 1) NC = 1;
    if (NC > B) NC = B;

    u16* Wth = (u16*)p;  u16* Wtl;
    if (wtAll) { Wtl = Wth + (size_t)36 * EE; p += wt12; }
    else       { Wtl = Wth + (size_t)3 * EE;  p += wt1;  }
    u16* Qh = (u16*)p; p += (size_t)NC * TE * 2;
    u16* Ql = (u16*)p; p += (size_t)NC * TE * 2;
    u16* Kh = (u16*)p; p += (size_t)NC * TE * 2;
    u16* Kl = (u16*)p; p += (size_t)NC * TE * 2;
    u16* Vh = (u16*)p; p += (size_t)NC * TE * 2;
    u16* Vl = (u16*)p; p += (size_t)NC * TE * 2;
    u16* Sh = (u16*)p; p += (size_t)NC * TT * 2;
    u16* Sl = (u16*)p; p += (size_t)NC * TT * 2;
    u16* Zallh = (u16*)p; if (tierA) p += (size_t)8 * 12 * TE * 2;
    u16* Zalll = (u16*)p;
    u16* Zh = Qh;   // alias: Q dead after scores GEMM
    u16* Zl = Ql;

    hipMemsetAsync(out, 0, (size_t)B * TE * sizeof(float), stream);
    hipMemsetAsync(zp, 0, 4096, stream);

    dim3 blk(256);

    // One-time operand splits.
    k_split<<<2048, blk, 0, stream>>>(x, Xh, Xl, (long long)B * TE);
    k_tsplit<<<dim3(E / 32, (int)HE / 32), blk, 0, stream>>>(WO, WOth, WOtl, (int)HE, E);
    if (wtAll)
        k_tsplitA<<<dim3(24, 24, 36), blk, 0, stream>>>(WQ, WK, WV, Wth, Wtl);

    // r8 loop structure: h outer, batch-chunks inner.
    for (int h = 0; h < H; ++h) {
        const int i_lo = (int)(((long long)h * TE) / HE);
        const long long aShift = (long long)i_lo * HE - (long long)h * TE;

        const u16* wh; const u16* wl;
        if (wtAll) { wh = Wth + (size_t)h * 3 * EE; wl = Wtl + (size_t)h * 3 * EE; }
        else {
            k_tsplit3<<<dim3(24, 24, 3), blk, 0, stream>>>(
                WQ + (size_t)h * EE, WK + (size_t)h * EE, WV + (size_t)h * EE,
                Wth, Wtl);
            wh = Wth; wl = Wtl;
        }

        for (int b0 = 0; b0 < B; b0 += NC) {
            const int nb = (B - b0 < NC) ? (B - b0) : NC;

            // Q/K/V projections: (nb*T x 768) @ (768 x 768), z innermost.
            g_qkv<<<dim3(18, nb * T / 128), blk, 0, stream>>>(
                Xh + (size_t)b0 * TE, Xl + (size_t)b0 * TE, wh, wl,
                Qh, Ql, Kh, Kl, Vh, Vl);

            // Scores: Q (1024x768) @ K-flat (768,1024) k-major, ldb=T.
            g_km<<<dim3(8, 8, nb), blk, 0, stream>>>(
                Qh, Ql, Kh, Kl, Sh, Sl, 768, 768, 1024, 1024, TE, TE, TT);

            // Softmax over query axis, 1/sqrt(T) pre-scale, 3-phase.
            sm_part<<<dim3(T / 256, RC, nb), blk, 0, stream>>>(Sh, Sl, part, T, 0.03125f);
            sm_fin2<<<dim3(T / 256, nb), blk, 0, stream>>>(part, finb, T);
            sm_norm<<<dim3(T / 256, RC, nb), blk, 0, stream>>>(Sh, Sl, finb, T, 0.03125f);

            if (tierA) {
                // Z -> Zall[b][h][t][dv] (batch stride 12*TE); final merged later.
                g_km<<<dim3(6, 8, nb), blk, 0, stream>>>(
                    Sh, Sl, Vh, Vl,
                    Zallh + (size_t)(b0 * 12 + h) * TE,
                    Zalll + (size_t)(b0 * 12 + h) * TE,
                    1024, 1024, 768, 768, TT, TE, 12 * TE);
            } else {
                // Z = A @ V into Q alias, then windowed final per head (r8).
                g_km<<<dim3(6, 8, nb), blk, 0, stream>>>(
                    Sh, Sl, Vh, Vl, Zh, Zl, 1024, 1024, 768, 768, TT, TE, TE);
                g_fin<<<dim3(6, 24, nb), blk, 0, stream>>>(
                    Zh, Zl, WOth, WOtl,
                    out + (size_t)b0 * TE + (size_t)i_lo * E, zp,
                    aShift, T - i_lo, 24);
            }
        }
    }

    if (tierA) {
        // Merged final: out[b] = reshape(Zall_b,(1024,9216)) @ WO, k-split 4.
        g_out<<<dim3(6, 8 * 4, 8), blk, 0, stream>>>(
            Zallh, Zalll, WOth, WOtl, out, 4);
    }
}

// Round 10
// 4081.733 us; speedup vs baseline: 2.0663x; 1.0193x over previous
//
#include <hip/hip_runtime.h>

// B=8, T=1024, E=768, H=12.
// Round 14 (base: r13 = 4160us measured). Two contained deltas:
//  1. g_qkv XCD-aware block remap: grp=flat/Mtiles, m=flat%Mtiles -- each
//     XCD owns m = xcd (mod 8) -> its 8 X-panels (3.2MB) stay L2-resident
//     all launch; W streams once per XCD. Predict FETCH 186->~120MB.
//  2. sm_fin2 merged into sm_norm (inline RC-reduce, r11-proven math):
//     -12 launches/iteration.
// Everything else byte-identical to r13.

typedef __bf16 bf16x8 __attribute__((ext_vector_type(8)));
typedef float  f32x4  __attribute__((ext_vector_type(4)));
typedef unsigned short u16;
typedef u16 u16x8 __attribute__((ext_vector_type(8)));
typedef u16 u16x4 __attribute__((ext_vector_type(4)));
typedef unsigned int u32;

#define RC 16   // row-chunks for 3-phase softmax

__device__ __forceinline__ float bf2f(u16 u) {
    union { u32 i; float f; } x; x.i = ((u32)u) << 16; return x.f;
}
__device__ __forceinline__ u16 f2bf(float f) {
    __bf16 h = (__bf16)f; union { __bf16 b; u16 u; } x; x.b = h; return x.u;
}
__device__ __forceinline__ void split2(float v, u16& h, u16& l) {
    h = f2bf(v); l = f2bf(v - bf2f(h));
}

__device__ __forceinline__ void gl16(const void* g, void* l) {
    __builtin_amdgcn_global_load_lds(
        (const __attribute__((address_space(1))) u32*)g,
        (__attribute__((address_space(3))) u32*)l, 16, 0, 0);
}

// ---------------- 128x128 split-bf16 core (r8-exact) ----------------
// A: hi/lo row-major (M x K, lda), staged via global_load_lds w16,
// source k pre-swizzled (conflict-free, verified r4).
// B: BKMAJ=0 -> B^T hi/lo row-major (N x K, ldb), same gl16 path.
//    BKMAJ=1 -> B hi/lo k-major (K x N, ldb), coalesced u16 loads +
//    swizzled ds_write_b128.
// WIN=1: per-lane A-source clamp to zero page (quirky flat window).
// mode: 0=C fp32 store, 1=hi/lo bf16 store, 2=atomicAdd fp32.
template<int BKMAJ, int WIN>
__device__ __forceinline__ void core(
    const u16* __restrict__ Ah, const u16* __restrict__ Al,
    const u16* __restrict__ Bh, const u16* __restrict__ Bl,
    float* __restrict__ C, u16* __restrict__ Ch, u16* __restrict__ Cl,
    int K, int lda, int ldb, int ldc,
    long long aShift, long long aHi, const u16* __restrict__ zp,
    int mClip, int mode, int mtile, int kChunk, int kChunks, int n0)
{
    __shared__ u16 Ahs[4096], Als[4096], Bhs[4096], Bls[4096]; // 32 KiB

    const int tid = threadIdx.x, lane = tid & 63, w = tid >> 6;
    const int m0 = mtile * 128;
    const int wm = (w & 1) << 6, wn = (w >> 1) << 6;
    const int lr = lane & 15, lq = lane >> 4;
    const int rs = (lr >> 1) & 3;
    const int fro = (lq ^ rs) << 4;            // frag byte offset in row

    // gl16 staging geometry: wave w covers LDS rows w*16..+15 (call 0)
    // and +64 (call 1); lane -> (row, 16B slot). Source k pre-swizzled.
    const int srow = (w << 4) + (lane >> 2);
    const int kk = (((lane & 3) ^ ((srow >> 1) & 3)) << 3);
    const int lds0 = (w << 10), lds1 = lds0 + 4096;

    // k-major B staging (scores / Z)
    const int nB = tid & 127, khB = (tid >> 7) << 4;
    const int rsB = (nB >> 1) & 3;
    const int sB0 = (((khB >> 3) ^ rsB) << 4);
    const int sB1 = ((((khB >> 3) | 1) ^ rsB) << 4);

    f32x4 acc[4][4] = {};
    const int kLen = K / kChunks;
    const int kBeg = kChunk * kLen, kEnd = kBeg + kLen;

    u16 rBh[16], rBl[16];
    auto loadB = [&](int k0) {
        if constexpr (BKMAJ) {
#pragma unroll
            for (int j = 0; j < 16; ++j) {
                long long o = (long long)(k0 + khB + j) * ldb + n0 + nB;
                rBh[j] = Bh[o]; rBl[j] = Bl[o];
            }
        }
    };
    auto stage = [&](int k0) {
        long long o1 = (long long)(m0 + srow) * lda + k0 + kk;
        long long o2 = o1 + (long long)64 * lda;
        const u16 *p1h = Ah + o1, *p1l = Al + o1;
        const u16 *p2h = Ah + o2, *p2l = Al + o2;
        if constexpr (WIN) {
            long long a1 = o1 + aShift, a2 = o2 + aShift;
            bool v1 = (a1 >= 0) && (a1 < aHi);
            bool v2 = (a2 >= 0) && (a2 < aHi);
            p1h = v1 ? Ah + a1 : zp;  p1l = v1 ? Al + a1 : zp;
            p2h = v2 ? Ah + a2 : zp;  p2l = v2 ? Al + a2 : zp;
        }
        gl16(p1h, (char*)Ahs + lds0);  gl16(p2h, (char*)Ahs + lds1);
        gl16(p1l, (char*)Als + lds0);  gl16(p2l, (char*)Als + lds1);
        if constexpr (!BKMAJ) {
            long long b1 = (long long)(n0 + srow) * ldb + k0 + kk;
            long long b2 = b1 + (long long)64 * ldb;
            gl16(Bh + b1, (char*)Bhs + lds0);  gl16(Bh + b2, (char*)Bhs + lds1);
            gl16(Bl + b1, (char*)Bls + lds0);  gl16(Bl + b2, (char*)Bls + lds1);
        }
    };
    auto writeB = [&]() {
        if constexpr (BKMAJ) {
            u16x8 h0, h1, l0, l1;
#pragma unroll
            for (int j = 0; j < 8; ++j) {
                h0[j] = rBh[j]; h1[j] = rBh[j + 8];
                l0[j] = rBl[j]; l1[j] = rBl[j + 8];
            }
            *(u16x8*)((char*)Bhs + nB * 64 + sB0) = h0;
            *(u16x8*)((char*)Bhs + nB * 64 + sB1) = h1;
            *(u16x8*)((char*)Bls + nB * 64 + sB0) = l0;
            *(u16x8*)((char*)Bls + nB * 64 + sB1) = l1;
        }
    };

    loadB(kBeg);
    for (int k0 = kBeg; k0 < kEnd; k0 += 32) {
        stage(k0);                       // async DMA into LDS (A, and B if !BKMAJ)
        writeB();                        // (BKMAJ) prefetched B -> LDS
        __syncthreads();                 // drains vmcnt + lgkmcnt
        if (k0 + 32 < kEnd) loadB(k0 + 32);   // (BKMAJ) prefetch next

        bf16x8 a_h[4], a_l[4];
#pragma unroll
        for (int mi = 0; mi < 4; ++mi) {
            int off = ((wm + (mi << 4) + lr) << 6) + fro;
            a_h[mi] = *(const bf16x8*)((char*)Ahs + off);
            a_l[mi] = *(const bf16x8*)((char*)Als + off);
        }
#pragma unroll
        for (int ni = 0; ni < 4; ++ni) {
            int off = ((wn + (ni << 4) + lr) << 6) + fro;
            bf16x8 b_h = *(const bf16x8*)((char*)Bhs + off);
            bf16x8 b_l = *(const bf16x8*)((char*)Bls + off);
#pragma unroll
            for (int mi = 0; mi < 4; ++mi) {
                acc[mi][ni] = __builtin_amdgcn_mfma_f32_16x16x32_bf16(a_h[mi], b_h, acc[mi][ni], 0, 0, 0);
                acc[mi][ni] = __builtin_amdgcn_mfma_f32_16x16x32_bf16(a_l[mi], b_h, acc[mi][ni], 0, 0, 0);
                acc[mi][ni] = __builtin_amdgcn_mfma_f32_16x16x32_bf16(a_h[mi], b_l, acc[mi][ni], 0, 0, 0);
            }
        }
        __syncthreads();
    }

    // Epilogue: C/D layout col = lane&15, row = (lane>>4)*4 + reg  [m89]
#pragma unroll
    for (int mi = 0; mi < 4; ++mi)
#pragma unroll
        for (int r = 0; r < 4; ++r) {
            int row = m0 + wm + (mi << 4) + (lq << 2) + r;
            if (row < mClip) {
#pragma unroll
                for (int ni = 0; ni < 4; ++ni) {
                    long long off = (long long)row * ldc + n0 + wn + (ni << 4) + lr;
                    float v = acc[mi][ni][r];
                    if (mode == 2)      atomicAdd(&C[off], v);
                    else if (mode == 1) { u16 hh, ll; split2(v, hh, ll); Ch[off] = hh; Cl[off] = ll; }
                    else                C[off] = v;
                }
            }
        }
}

// Fused QKV: grid (18, Mtiles). XCD-aware remap: dispatch-order flat id
// flat = y*18 + x; grp = flat / Mtiles selects (z, n-tile) -- 64 consecutive
// blocks share one W-panel; m = flat % Mtiles. Each XCD then owns
// m = xcd (mod 8): its 8 X-panels (3.2 MB) stay L2-resident all launch.
__global__ __launch_bounds__(256, 4)
void g_qkv(const u16* __restrict__ Xh, const u16* __restrict__ Xl,
           const u16* __restrict__ Wth, const u16* __restrict__ Wtl,
           u16* __restrict__ Qh, u16* __restrict__ Ql,
           u16* __restrict__ Kh, u16* __restrict__ Kl,
           u16* __restrict__ Vh, u16* __restrict__ Vl)
{
    const long long EE = 768LL * 768;
    const int mT = gridDim.y;                      // total m-tiles
    int flat = blockIdx.y * 18 + blockIdx.x;       // dispatch-linear id
    int mt   = flat % mT;
    int grp  = flat / mT;                          // 0..17
    int z    = grp % 3;
    int n0   = (grp / 3) * 128;
    const u16* bh = Wth + (long long)z * EE;
    const u16* bl = Wtl + (long long)z * EE;
    u16* ch = (z == 0) ? Qh : (z == 1) ? Kh : Vh;
    u16* cl = (z == 0) ? Ql : (z == 1) ? Kl : Vl;
    core<0, 0>(Xh, Xl, bh, bl, nullptr, ch, cl, 768, 768, 768, 768,
               0, 0, nullptr, 1 << 30, 1, mt, 0, 1, n0);
}

// k-major-B GEMM (scores: B = K-flat (768,1024); Z: B = V). [r8-exact]
__global__ __launch_bounds__(256, 3)
void g_km(const u16* __restrict__ Ah, const u16* __restrict__ Al,
          const u16* __restrict__ Bh, const u16* __restrict__ Bl,
          u16* __restrict__ Ch, u16* __restrict__ Cl,
          int K, int lda, int ldb, int ldc,
          long long sA, long long sB, long long sC)
{
    long long z = blockIdx.z;
    core<1, 0>(Ah + z * sA, Al + z * sA, Bh + z * sB, Bl + z * sB,
               nullptr, Ch + z * sC, Cl + z * sC,
               K, lda, ldb, ldc, 0, 0, nullptr, 1 << 30, 1,
               blockIdx.y, 0, 1, blockIdx.x * 128);
}

// Merged final projection (tierA, NC==8 only): out[b] = Zall_b(1024,9216)@WO.
__global__ __launch_bounds__(256, 3)
void g_out(const u16* __restrict__ Zh, const u16* __restrict__ Zl,
           const u16* __restrict__ WOth, const u16* __restrict__ WOtl,
           float* __restrict__ C, int kChunks)
{
    const long long ZB = 12LL * 786432;
    long long z = blockIdx.z;
    int mtile = blockIdx.y / kChunks;
    int kc    = blockIdx.y % kChunks;
    core<0, 0>(Zh + z * ZB, Zl + z * ZB, WOth, WOtl, C + z * 786432LL,
               nullptr, nullptr, 9216, 9216, 9216, 768,
               0, 0, nullptr, 1 << 30, 2, mtile, kc, kChunks, blockIdx.x * 128);
}

// Final projection: windowed A (quirky flat reshape), k-split + atomics. [r8]
__global__ __launch_bounds__(256, 3)
void g_fin(const u16* __restrict__ Zh, const u16* __restrict__ Zl,
           const u16* __restrict__ WOth, const u16* __restrict__ WOtl,
           float* __restrict__ C, const u16* __restrict__ zp,
           long long aShift, int mClip, int kChunks)
{
    const long long TE_ = 786432;
    long long z = blockIdx.z;
    core<0, 1>(Zh + z * TE_, Zl + z * TE_, WOth, WOtl, C + z * TE_,
               nullptr, nullptr, 9216, 9216, 9216, 768,
               aShift, TE_, zp, mClip, 2, 0, blockIdx.y, kChunks, blockIdx.x * 128);
}

// fp32 -> (hi,lo) bf16, flat.
__global__ void k_split(const float* __restrict__ s, u16* __restrict__ h,
                        u16* __restrict__ l, long long n)
{
    long long i = ((long long)blockIdx.x * blockDim.x + threadIdx.x) * 4;
    long long stride = (long long)gridDim.x * blockDim.x * 4;
    for (; i < n; i += stride) {
        float4 v = *(const float4*)(s + i);
        u16x4 hh, ll;
        u16 h0, l0, h1, l1, h2, l2, h3, l3;
        split2(v.x, h0, l0); split2(v.y, h1, l1);
        split2(v.z, h2, l2); split2(v.w, h3, l3);
        hh[0] = h0; hh[1] = h1; hh[2] = h2; hh[3] = h3;
        ll[0] = l0; ll[1] = l1; ll[2] = l2; ll[3] = l3;
        *(u16x4*)(h + i) = hh;
        *(u16x4*)(l + i) = ll;
    }
}

// fp32 (Ks x Ns) -> transposed (Ns x Ks) hi/lo bf16.
__global__ void k_tsplit(const float* __restrict__ s, u16* __restrict__ dh,
                         u16* __restrict__ dl, int Ks, int Ns)
{
    __shared__ float t[32][33];
    int tx = threadIdx.x & 31, ty = threadIdx.x >> 5;
    int kb = blockIdx.y << 5, nb_ = blockIdx.x << 5;
#pragma unroll
    for (int i = 0; i < 4; ++i)
        t[ty + 8 * i][tx] = s[(long long)(kb + ty + 8 * i) * Ns + nb_ + tx];
    __syncthreads();
#pragma unroll
    for (int i = 0; i < 4; ++i) {
        float v = t[tx][ty + 8 * i];
        long long o = (long long)(nb_ + ty + 8 * i) * Ks + kb + tx;
        u16 hh, ll; split2(v, hh, ll);
        dh[o] = hh; dl[o] = ll;
    }
}

// Per-head W transpose-split (fallback): z selects WQ/WK/WV; dst += z*E*E.
__global__ void k_tsplit3(const float* __restrict__ s0, const float* __restrict__ s1,
                          const float* __restrict__ s2,
                          u16* __restrict__ dh, u16* __restrict__ dl)
{
    const int E = 768; const long long EE = (long long)E * E;
    const float* s = (blockIdx.z == 0) ? s0 : (blockIdx.z == 1) ? s1 : s2;
    u16* h = dh + blockIdx.z * EE;
    u16* l = dl + blockIdx.z * EE;
    __shared__ float t[32][33];
    int tx = threadIdx.x & 31, ty = threadIdx.x >> 5;
    int kb = blockIdx.y << 5, nb_ = blockIdx.x << 5;
#pragma unroll
    for (int i = 0; i < 4; ++i)
        t[ty + 8 * i][tx] = s[(long long)(kb + ty + 8 * i) * E + nb_ + tx];
    __syncthreads();
#pragma unroll
    for (int i = 0; i < 4; ++i) {
        float v = t[tx][ty + 8 * i];
        long long o = (long long)(nb_ + ty + 8 * i) * E + kb + tx;
        u16 hh, ll; split2(v, hh, ll);
        h[o] = hh; l[o] = ll;
    }
}

// All-heads W transpose-split (cold path): z = h*3 + w; one launch.
__global__ void k_tsplitA(const float* __restrict__ WQ, const float* __restrict__ WK,
                          const float* __restrict__ WV,
                          u16* __restrict__ dh, u16* __restrict__ dl)
{
    const int E = 768; const long long EE = (long long)E * E;
    int hz = blockIdx.z, hh_ = hz / 3, w = hz % 3;
    const float* s = ((w == 0) ? WQ : (w == 1) ? WK : WV) + (long long)hh_ * EE;
    u16* h = dh + (long long)hz * EE;
    u16* l = dl + (long long)hz * EE;
    __shared__ float t[32][33];
    int tx = threadIdx.x & 31, ty = threadIdx.x >> 5;
    int kb = blockIdx.y << 5, nb_ = blockIdx.x << 5;
#pragma unroll
    for (int i = 0; i < 4; ++i)
        t[ty + 8 * i][tx] = s[(long long)(kb + ty + 8 * i) * E + nb_ + tx];
    __syncthreads();
#pragma unroll
    for (int i = 0; i < 4; ++i) {
        float v = t[tx][ty + 8 * i];
        long long o = (long long)(nb_ + ty + 8 * i) * E + kb + tx;
        u16 hh, ll; split2(v, hh, ll);
        h[o] = hh; l[o] = ll;
    }
}

// ---------------- 2-phase column softmax (query-axis) ----------------
// Phase A [r8-exact]: per-(column, row-chunk) partial (max, sum).
__global__ __launch_bounds__(256)
void sm_part(const u16* __restrict__ Sh, const u16* __restrict__ Sl,
             float2* __restrict__ part, int T, float scale)
{
    const int lane = threadIdx.x & 63, seg = threadIdx.x >> 6;
    const int j0 = blockIdx.x * 256 + lane * 4;
    const long long base = (long long)blockIdx.z * T * T;
    const int rpc = T / RC, rps = rpc / 4;
    const int r0 = blockIdx.y * rpc + seg * rps;

    float m[4] = {-3.4e38f, -3.4e38f, -3.4e38f, -3.4e38f};
    float s[4] = {0.f, 0.f, 0.f, 0.f};
    for (int r = 0; r < rps; ++r) {
        long long o = base + (long long)(r0 + r) * T + j0;
        u16x4 vh = *(const u16x4*)(Sh + o);
        u16x4 vl = *(const u16x4*)(Sl + o);
#pragma unroll
        for (int c = 0; c < 4; ++c) {
            float v = (bf2f(vh[c]) + bf2f(vl[c])) * scale;
            float mn = fmaxf(m[c], v);
            s[c] = s[c] * __expf(m[c] - mn) + __expf(v - mn);
            m[c] = mn;
        }
    }
    __shared__ float4 smm[4][64], sss[4][64];
    smm[seg][lane] = make_float4(m[0], m[1], m[2], m[3]);
    sss[seg][lane] = make_float4(s[0], s[1], s[2], s[3]);
    __syncthreads();
    if (seg == 0) {
#pragma unroll
        for (int q = 1; q < 4; ++q) {
            float4 mq4 = smm[q][lane], sq4 = sss[q][lane];
            float mq[4] = {mq4.x, mq4.y, mq4.z, mq4.w};
            float sq[4] = {sq4.x, sq4.y, sq4.z, sq4.w};
#pragma unroll
            for (int c = 0; c < 4; ++c) {
                float mn = fmaxf(m[c], mq[c]);
                s[c] = s[c] * __expf(m[c] - mn) + sq[c] * __expf(mq[c] - mn);
                m[c] = mn;
            }
        }
        long long pb = ((long long)blockIdx.z * RC + blockIdx.y) * T + j0;
#pragma unroll
        for (int c = 0; c < 4; ++c)
            part[pb + c] = make_float2(m[c], s[c]);
    }
}

// Phase B: normalize in place; reduces the RC partials inline (16x redundant
// on a 1 MB L2-hot buffer -- replaces the separate sm_fin2 launch).
__global__ __launch_bounds__(256)
void sm_norm(u16* __restrict__ Sh, u16* __restrict__ Sl,
             const float2* __restrict__ part, int T, float scale)
{
    const int lane = threadIdx.x & 63, seg = threadIdx.x >> 6;
    const int j0 = blockIdx.x * 256 + lane * 4;
    const long long base = (long long)blockIdx.z * T * T;
    const int rpc = T / RC, rps = rpc / 4;
    const int r0 = blockIdx.y * rpc + seg * rps;
    float mt[4], inv[4];
#pragma unroll
    for (int c = 0; c < 4; ++c) {
        float m = -3.4e38f, s = 0.f;
#pragma unroll
        for (int q = 0; q < RC; ++q) {
            float2 p = part[((long long)blockIdx.z * RC + q) * T + j0 + c];
            float mn = fmaxf(m, p.x);
            s = s * __expf(m - mn) + p.y * __expf(p.x - mn);
            m = mn;
        }
        mt[c] = m; inv[c] = 1.f / s;
    }
    for (int r = 0; r < rps; ++r) {
        long long o = base + (long long)(r0 + r) * T + j0;
        u16x4 vh = *(const u16x4*)(Sh + o);
        u16x4 vl = *(const u16x4*)(Sl + o);
        u16x4 oh, ol;
#pragma unroll
        for (int c = 0; c < 4; ++c) {
            float v = (bf2f(vh[c]) + bf2f(vl[c])) * scale;
            float p = __expf(v - mt[c]) * inv[c];
            u16 hh, ll; split2(p, hh, ll);
            oh[c] = hh; ol[c] = ll;
        }
        *(u16x4*)(Sh + o) = oh;
        *(u16x4*)(Sl + o) = ol;
    }
}

extern "C" void kernel_launch(void* const* d_in, const int* in_sizes, int n_in,
                              void* d_out, int out_size, void* d_ws, size_t ws_size,
                              hipStream_t stream)
{
    const float* x  = (const float*)d_in[0];   // (B,T,E)
    const float* WQ = (const float*)d_in[1];   // (H,E,E)
    const float* WK = (const float*)d_in[2];
    const float* WV = (const float*)d_in[3];
    const float* WO = (const float*)d_in[4];   // (H*E, E)
    float* out = (float*)d_out;                // (B,T,E)

    const int B = 8, T = 1024, E = 768, H = 12;
    const long long TE = (long long)T * E;     // 786432
    const long long TT = (long long)T * T;     // 1048576
    const long long HE = (long long)H * E;     // 9216
    const long long EE = (long long)E * E;

    // ---- fixed workspace (r13 layout) ----
    char* p = (char*)d_ws;
    u16* Xh   = (u16*)p; p += (size_t)B * TE * 2;
    u16* Xl   = (u16*)p; p += (size_t)B * TE * 2;
    u16* WOth = (u16*)p; p += (size_t)E * HE * 2;
    u16* WOtl = (u16*)p; p += (size_t)E * HE * 2;
    u16* zp   = (u16*)p; p += 4096;
    float2* part = (float2*)p; p += (size_t)B * RC * T * sizeof(float2); // 1 MB
    size_t used0 = (size_t)(p - (char*)d_ws);

    const size_t slice = (size_t)(6 * TE + 2 * TT) * 2;  // Q,K,V,S hi/lo: 13.6 MB
    const size_t zsl   = (size_t)12 * TE * 4;            // Zall/batch: 37.7 MB
    const size_t wt12  = (size_t)36 * EE * 2 * 2;        // 85 MB
    const size_t wt1   = (size_t)3 * EE * 2 * 2;         // 7 MB

    long long avail = (long long)ws_size - (long long)used0;

    // tierA strictly requires the FULL NC=8 configuration (r12 lesson).
    const bool tierA = avail >= (long long)(wt12 + 8 * (slice + zsl));
    const bool wtAll = tierA || avail >= (long long)(wt12 + 8 * slice);

    long long wsliceF = avail - (long long)(wtAll ? wt12 : wt1);
    int NC = (int)(wsliceF / (long long)slice);
    if (NC < 1) NC = 1;
    if (NC > B) NC = B;

    u16* Wth = (u16*)p;  u16* Wtl;
    if (wtAll) { Wtl = Wth + (size_t)36 * EE; p += wt12; }
    else       { Wtl = Wth + (size_t)3 * EE;  p += wt1;  }
    u16* Qh = (u16*)p; p += (size_t)NC * TE * 2;
    u16* Ql = (u16*)p; p += (size_t)NC * TE * 2;
    u16* Kh = (u16*)p; p += (size_t)NC * TE * 2;
    u16* Kl = (u16*)p; p += (size_t)NC * TE * 2;
    u16* Vh = (u16*)p; p += (size_t)NC * TE * 2;
    u16* Vl = (u16*)p; p += (size_t)NC * TE * 2;
    u16* Sh = (u16*)p; p += (size_t)NC * TT * 2;
    u16* Sl = (u16*)p; p += (size_t)NC * TT * 2;
    u16* Zallh = (u16*)p; if (tierA) p += (size_t)8 * 12 * TE * 2;
    u16* Zalll = (u16*)p;
    u16* Zh = Qh;   // alias: Q dead after scores GEMM
    u16* Zl = Ql;

    hipMemsetAsync(out, 0, (size_t)B * TE * sizeof(float), stream);
    hipMemsetAsync(zp, 0, 4096, stream);

    dim3 blk(256);

    // One-time operand splits.
    k_split<<<2048, blk, 0, stream>>>(x, Xh, Xl, (long long)B * TE);
    k_tsplit<<<dim3(E / 32, (int)HE / 32), blk, 0, stream>>>(WO, WOth, WOtl, (int)HE, E);
    if (wtAll)
        k_tsplitA<<<dim3(24, 24, 36), blk, 0, stream>>>(WQ, WK, WV, Wth, Wtl);

    // h outer, batch-chunks inner (r8 structure).
    for (int h = 0; h < H; ++h) {
        const int i_lo = (int)(((long long)h * TE) / HE);
        const long long aShift = (long long)i_lo * HE - (long long)h * TE;

        const u16* wh; const u16* wl;
        if (wtAll) { wh = Wth + (size_t)h * 3 * EE; wl = Wtl + (size_t)h * 3 * EE; }
        else {
            k_tsplit3<<<dim3(24, 24, 3), blk, 0, stream>>>(
                WQ + (size_t)h * EE, WK + (size_t)h * EE, WV + (size_t)h * EE,
                Wth, Wtl);
            wh = Wth; wl = Wtl;
        }

        for (int b0 = 0; b0 < B; b0 += NC) {
            const int nb = (B - b0 < NC) ? (B - b0) : NC;

            // Q/K/V projections: (nb*T x 768) @ (768 x 768), XCD-aware remap.
            g_qkv<<<dim3(18, nb * T / 128), blk, 0, stream>>>(
                Xh + (size_t)b0 * TE, Xl + (size_t)b0 * TE, wh, wl,
                Qh, Ql, Kh, Kl, Vh, Vl);

            // Scores: Q (1024x768) @ K-flat (768,1024) k-major, ldb=T.
            g_km<<<dim3(8, 8, nb), blk, 0, stream>>>(
                Qh, Ql, Kh, Kl, Sh, Sl, 768, 768, 1024, 1024, TE, TE, TT);

            // Softmax over query axis, 1/sqrt(T) pre-scale, 2-phase.
            sm_part<<<dim3(T / 256, RC, nb), blk, 0, stream>>>(Sh, Sl, part, T, 0.03125f);
            sm_norm<<<dim3(T / 256, RC, nb), blk, 0, stream>>>(Sh, Sl, part, T, 0.03125f);

            if (tierA) {
                g_km<<<dim3(6, 8, nb), blk, 0, stream>>>(
                    Sh, Sl, Vh, Vl,
                    Zallh + (size_t)(b0 * 12 + h) * TE,
                    Zalll + (size_t)(b0 * 12 + h) * TE,
                    1024, 1024, 768, 768, TT, TE, 12 * TE);
            } else {
                g_km<<<dim3(6, 8, nb), blk, 0, stream>>>(
                    Sh, Sl, Vh, Vl, Zh, Zl, 1024, 1024, 768, 768, TT, TE, TE);
                g_fin<<<dim3(6, 24, nb), blk, 0, stream>>>(
                    Zh, Zl, WOth, WOtl,
                    out + (size_t)b0 * TE + (size_t)i_lo * E, zp,
                    aShift, T - i_lo, 24);
            }
        }
    }

    if (tierA) {
        g_out<<<dim3(6, 8 * 4, 8), blk, 0, stream>>>(
            Zallh, Zalll, WOth, WOtl, out, 4);
    }
}

// Round 11
// 3748.838 us; speedup vs baseline: 2.2498x; 1.0888x over previous
//
#include <hip/hip_runtime.h>

// B=8, T=1024, E=768, H=12.
// Round 15 (base: r14 = 4081us measured). Two deltas:
//  1. Scores GEMM fused softmax-partials via COMPILE-TIME template<SMAX>
//     (r7's runtime-mode version spilled; if constexpr keeps all other
//     instantiations bit-identical to the proven code). Deletes sm_part.
//  2. g_fin kChunks 24->12 (halves atomic RMW; 576 blocks = 2.25/CU).
// Everything else byte-identical to r14.

typedef __bf16 bf16x8 __attribute__((ext_vector_type(8)));
typedef float  f32x4  __attribute__((ext_vector_type(4)));
typedef unsigned short u16;
typedef u16 u16x8 __attribute__((ext_vector_type(8)));
typedef u16 u16x4 __attribute__((ext_vector_type(4)));
typedef unsigned int u32;

#define RC 16   // softmax partials per column (8 mtiles x 2 wave-halves)

__device__ __forceinline__ float bf2f(u16 u) {
    union { u32 i; float f; } x; x.i = ((u32)u) << 16; return x.f;
}
__device__ __forceinline__ u16 f2bf(float f) {
    __bf16 h = (__bf16)f; union { __bf16 b; u16 u; } x; x.b = h; return x.u;
}
__device__ __forceinline__ void split2(float v, u16& h, u16& l) {
    h = f2bf(v); l = f2bf(v - bf2f(h));
}

__device__ __forceinline__ void gl16(const void* g, void* l) {
    __builtin_amdgcn_global_load_lds(
        (const __attribute__((address_space(1))) u32*)g,
        (__attribute__((address_space(3))) u32*)l, 16, 0, 0);
}

// ---------------- 128x128 split-bf16 core ----------------
// A: hi/lo row-major (M x K, lda), staged via global_load_lds w16,
// source k pre-swizzled (conflict-free, verified r4).
// B: BKMAJ=0 -> B^T hi/lo row-major (N x K, ldb), same gl16 path.
//    BKMAJ=1 -> B hi/lo k-major (K x N, ldb), coalesced u16 loads +
//    swizzled ds_write_b128.
// WIN=1: per-lane A-source clamp to zero page (quirky flat window).
// SMAX=1: (compile-time) scores epilogue also emits per-column softmax
//    partials (m, s) into part -- only the g_sc instantiation pays.
// mode: 0=C fp32 store, 1=hi/lo bf16 store, 2=atomicAdd fp32.
template<int BKMAJ, int WIN, int SMAX>
__device__ __forceinline__ void core(
    const u16* __restrict__ Ah, const u16* __restrict__ Al,
    const u16* __restrict__ Bh, const u16* __restrict__ Bl,
    float* __restrict__ C, u16* __restrict__ Ch, u16* __restrict__ Cl,
    int K, int lda, int ldb, int ldc,
    long long aShift, long long aHi, const u16* __restrict__ zp,
    int mClip, int mode, int mtile, int kChunk, int kChunks, int n0,
    float2* __restrict__ part, float pscale, int pz)
{
    __shared__ u16 Ahs[4096], Als[4096], Bhs[4096], Bls[4096]; // 32 KiB

    const int tid = threadIdx.x, lane = tid & 63, w = tid >> 6;
    const int m0 = mtile * 128;
    const int wm = (w & 1) << 6, wn = (w >> 1) << 6;
    const int lr = lane & 15, lq = lane >> 4;
    const int rs = (lr >> 1) & 3;
    const int fro = (lq ^ rs) << 4;            // frag byte offset in row

    // gl16 staging geometry: wave w covers LDS rows w*16..+15 (call 0)
    // and +64 (call 1); lane -> (row, 16B slot). Source k pre-swizzled.
    const int srow = (w << 4) + (lane >> 2);
    const int kk = (((lane & 3) ^ ((srow >> 1) & 3)) << 3);
    const int lds0 = (w << 10), lds1 = lds0 + 4096;

    // k-major B staging (scores / Z)
    const int nB = tid & 127, khB = (tid >> 7) << 4;
    const int rsB = (nB >> 1) & 3;
    const int sB0 = (((khB >> 3) ^ rsB) << 4);
    const int sB1 = ((((khB >> 3) | 1) ^ rsB) << 4);

    f32x4 acc[4][4] = {};
    const int kLen = K / kChunks;
    const int kBeg = kChunk * kLen, kEnd = kBeg + kLen;

    u16 rBh[16], rBl[16];
    auto loadB = [&](int k0) {
        if constexpr (BKMAJ) {
#pragma unroll
            for (int j = 0; j < 16; ++j) {
                long long o = (long long)(k0 + khB + j) * ldb + n0 + nB;
                rBh[j] = Bh[o]; rBl[j] = Bl[o];
            }
        }
    };
    auto stage = [&](int k0) {
        long long o1 = (long long)(m0 + srow) * lda + k0 + kk;
        long long o2 = o1 + (long long)64 * lda;
        const u16 *p1h = Ah + o1, *p1l = Al + o1;
        const u16 *p2h = Ah + o2, *p2l = Al + o2;
        if constexpr (WIN) {
            long long a1 = o1 + aShift, a2 = o2 + aShift;
            bool v1 = (a1 >= 0) && (a1 < aHi);
            bool v2 = (a2 >= 0) && (a2 < aHi);
            p1h = v1 ? Ah + a1 : zp;  p1l = v1 ? Al + a1 : zp;
            p2h = v2 ? Ah + a2 : zp;  p2l = v2 ? Al + a2 : zp;
        }
        gl16(p1h, (char*)Ahs + lds0);  gl16(p2h, (char*)Ahs + lds1);
        gl16(p1l, (char*)Als + lds0);  gl16(p2l, (char*)Als + lds1);
        if constexpr (!BKMAJ) {
            long long b1 = (long long)(n0 + srow) * ldb + k0 + kk;
            long long b2 = b1 + (long long)64 * ldb;
            gl16(Bh + b1, (char*)Bhs + lds0);  gl16(Bh + b2, (char*)Bhs + lds1);
            gl16(Bl + b1, (char*)Bls + lds0);  gl16(Bl + b2, (char*)Bls + lds1);
        }
    };
    auto writeB = [&]() {
        if constexpr (BKMAJ) {
            u16x8 h0, h1, l0, l1;
#pragma unroll
            for (int j = 0; j < 8; ++j) {
                h0[j] = rBh[j]; h1[j] = rBh[j + 8];
                l0[j] = rBl[j]; l1[j] = rBl[j + 8];
            }
            *(u16x8*)((char*)Bhs + nB * 64 + sB0) = h0;
            *(u16x8*)((char*)Bhs + nB * 64 + sB1) = h1;
            *(u16x8*)((char*)Bls + nB * 64 + sB0) = l0;
            *(u16x8*)((char*)Bls + nB * 64 + sB1) = l1;
        }
    };

    loadB(kBeg);
    for (int k0 = kBeg; k0 < kEnd; k0 += 32) {
        stage(k0);                       // async DMA into LDS (A, and B if !BKMAJ)
        writeB();                        // (BKMAJ) prefetched B -> LDS
        __syncthreads();                 // drains vmcnt + lgkmcnt
        if (k0 + 32 < kEnd) loadB(k0 + 32);   // (BKMAJ) prefetch next

        bf16x8 a_h[4], a_l[4];
#pragma unroll
        for (int mi = 0; mi < 4; ++mi) {
            int off = ((wm + (mi << 4) + lr) << 6) + fro;
            a_h[mi] = *(const bf16x8*)((char*)Ahs + off);
            a_l[mi] = *(const bf16x8*)((char*)Als + off);
        }
#pragma unroll
        for (int ni = 0; ni < 4; ++ni) {
            int off = ((wn + (ni << 4) + lr) << 6) + fro;
            bf16x8 b_h = *(const bf16x8*)((char*)Bhs + off);
            bf16x8 b_l = *(const bf16x8*)((char*)Bls + off);
#pragma unroll
            for (int mi = 0; mi < 4; ++mi) {
                acc[mi][ni] = __builtin_amdgcn_mfma_f32_16x16x32_bf16(a_h[mi], b_h, acc[mi][ni], 0, 0, 0);
                acc[mi][ni] = __builtin_amdgcn_mfma_f32_16x16x32_bf16(a_l[mi], b_h, acc[mi][ni], 0, 0, 0);
                acc[mi][ni] = __builtin_amdgcn_mfma_f32_16x16x32_bf16(a_h[mi], b_l, acc[mi][ni], 0, 0, 0);
            }
        }
        __syncthreads();
    }

    // Epilogue: C/D layout col = lane&15, row = (lane>>4)*4 + reg  [m89]
#pragma unroll
    for (int mi = 0; mi < 4; ++mi)
#pragma unroll
        for (int r = 0; r < 4; ++r) {
            int row = m0 + wm + (mi << 4) + (lq << 2) + r;
            if (row < mClip) {
#pragma unroll
                for (int ni = 0; ni < 4; ++ni) {
                    long long off = (long long)row * ldc + n0 + wn + (ni << 4) + lr;
                    float v = acc[mi][ni][r];
                    if (mode == 2)      atomicAdd(&C[off], v);
                    else if (mode == 1) { u16 hh, ll; split2(v, hh, ll); Ch[off] = hh; Cl[off] = ll; }
                    else                C[off] = v;
                }
            }
        }

    // SMAX epilogue: per-column softmax partials (m, s). Wave's 64 rows of
    // column j live in 16 acc values (mi x r) per lane across 4 lq lanes.
    // Two-pass local reduce + shfl_xor(16,32) over lq; lq==0 writes
    // part[pz][mtile*2 + (wm>>6)][j].  (Scores-only: N total = 1024.)
    if constexpr (SMAX) {
#pragma unroll
        for (int ni = 0; ni < 4; ++ni) {
            float mloc = -3.4e38f;
#pragma unroll
            for (int mi = 0; mi < 4; ++mi)
#pragma unroll
                for (int r = 0; r < 4; ++r)
                    mloc = fmaxf(mloc, acc[mi][ni][r]);
            mloc *= pscale;              // pscale > 0: max commutes
            float sl = 0.f;
#pragma unroll
            for (int mi = 0; mi < 4; ++mi)
#pragma unroll
                for (int r = 0; r < 4; ++r)
                    sl += __expf(acc[mi][ni][r] * pscale - mloc);
#pragma unroll
            for (int off = 16; off < 64; off <<= 1) {
                float mo = __shfl_xor(mloc, off);
                float so = __shfl_xor(sl, off);
                float mn = fmaxf(mloc, mo);
                sl = sl * __expf(mloc - mn) + so * __expf(mo - mn);
                mloc = mn;
            }
            if (lq == 0) {
                int j = n0 + wn + (ni << 4) + lr;
                part[((long long)pz * RC + (mtile << 1) + (wm >> 6)) * 1024 + j]
                    = make_float2(mloc, sl);
            }
        }
    }
}

// Fused QKV: grid (18, Mtiles). XCD-aware remap [r14-verified: FETCH
// 186->64MB]: grp = flat/Mtiles selects (z, n-tile); m = flat%Mtiles.
__global__ __launch_bounds__(256, 4)
void g_qkv(const u16* __restrict__ Xh, const u16* __restrict__ Xl,
           const u16* __restrict__ Wth, const u16* __restrict__ Wtl,
           u16* __restrict__ Qh, u16* __restrict__ Ql,
           u16* __restrict__ Kh, u16* __restrict__ Kl,
           u16* __restrict__ Vh, u16* __restrict__ Vl)
{
    const long long EE = 768LL * 768;
    const int mT = gridDim.y;
    int flat = blockIdx.y * 18 + blockIdx.x;
    int mt   = flat % mT;
    int grp  = flat / mT;
    int z    = grp % 3;
    int n0   = (grp / 3) * 128;
    const u16* bh = Wth + (long long)z * EE;
    const u16* bl = Wtl + (long long)z * EE;
    u16* ch = (z == 0) ? Qh : (z == 1) ? Kh : Vh;
    u16* cl = (z == 0) ? Ql : (z == 1) ? Kl : Vl;
    core<0, 0, 0>(Xh, Xl, bh, bl, nullptr, ch, cl, 768, 768, 768, 768,
                  0, 0, nullptr, 1 << 30, 1, mt, 0, 1, n0,
                  nullptr, 0.f, 0);
}

// k-major-B GEMM (Z: B = V). [r8-exact]
__global__ __launch_bounds__(256, 3)
void g_km(const u16* __restrict__ Ah, const u16* __restrict__ Al,
          const u16* __restrict__ Bh, const u16* __restrict__ Bl,
          u16* __restrict__ Ch, u16* __restrict__ Cl,
          int K, int lda, int ldb, int ldc,
          long long sA, long long sB, long long sC)
{
    long long z = blockIdx.z;
    core<1, 0, 0>(Ah + z * sA, Al + z * sA, Bh + z * sB, Bl + z * sB,
                  nullptr, Ch + z * sC, Cl + z * sC,
                  K, lda, ldb, ldc, 0, 0, nullptr, 1 << 30, 1,
                  blockIdx.y, 0, 1, blockIdx.x * 128,
                  nullptr, 0.f, 0);
}

// Scores GEMM with fused softmax partials (compile-time SMAX=1).
__global__ __launch_bounds__(256, 3)
void g_sc(const u16* __restrict__ Ah, const u16* __restrict__ Al,
          const u16* __restrict__ Bh, const u16* __restrict__ Bl,
          u16* __restrict__ Ch, u16* __restrict__ Cl,
          float2* __restrict__ part,
          int K, int lda, int ldb, int ldc,
          long long sA, long long sB, long long sC, float pscale)
{
    long long z = blockIdx.z;
    core<1, 0, 1>(Ah + z * sA, Al + z * sA, Bh + z * sB, Bl + z * sB,
                  nullptr, Ch + z * sC, Cl + z * sC,
                  K, lda, ldb, ldc, 0, 0, nullptr, 1 << 30, 1,
                  blockIdx.y, 0, 1, blockIdx.x * 128,
                  part, pscale, (int)z);
}

// Merged final projection (tierA, NC==8 only): out[b] = Zall_b(1024,9216)@WO.
__global__ __launch_bounds__(256, 3)
void g_out(const u16* __restrict__ Zh, const u16* __restrict__ Zl,
           const u16* __restrict__ WOth, const u16* __restrict__ WOtl,
           float* __restrict__ C, int kChunks)
{
    const long long ZB = 12LL * 786432;
    long long z = blockIdx.z;
    int mtile = blockIdx.y / kChunks;
    int kc    = blockIdx.y % kChunks;
    core<0, 0, 0>(Zh + z * ZB, Zl + z * ZB, WOth, WOtl, C + z * 786432LL,
                  nullptr, nullptr, 9216, 9216, 9216, 768,
                  0, 0, nullptr, 1 << 30, 2, mtile, kc, kChunks, blockIdx.x * 128,
                  nullptr, 0.f, 0);
}

// Final projection: windowed A (quirky flat reshape), k-split + atomics. [r8]
__global__ __launch_bounds__(256, 3)
void g_fin(const u16* __restrict__ Zh, const u16* __restrict__ Zl,
           const u16* __restrict__ WOth, const u16* __restrict__ WOtl,
           float* __restrict__ C, const u16* __restrict__ zp,
           long long aShift, int mClip, int kChunks)
{
    const long long TE_ = 786432;
    long long z = blockIdx.z;
    core<0, 1, 0>(Zh + z * TE_, Zl + z * TE_, WOth, WOtl, C + z * TE_,
                  nullptr, nullptr, 9216, 9216, 9216, 768,
                  aShift, TE_, zp, mClip, 2, 0, blockIdx.y, kChunks, blockIdx.x * 128,
                  nullptr, 0.f, 0);
}

// fp32 -> (hi,lo) bf16, flat.
__global__ void k_split(const float* __restrict__ s, u16* __restrict__ h,
                        u16* __restrict__ l, long long n)
{
    long long i = ((long long)blockIdx.x * blockDim.x + threadIdx.x) * 4;
    long long stride = (long long)gridDim.x * blockDim.x * 4;
    for (; i < n; i += stride) {
        float4 v = *(const float4*)(s + i);
        u16x4 hh, ll;
        u16 h0, l0, h1, l1, h2, l2, h3, l3;
        split2(v.x, h0, l0); split2(v.y, h1, l1);
        split2(v.z, h2, l2); split2(v.w, h3, l3);
        hh[0] = h0; hh[1] = h1; hh[2] = h2; hh[3] = h3;
        ll[0] = l0; ll[1] = l1; ll[2] = l2; ll[3] = l3;
        *(u16x4*)(h + i) = hh;
        *(u16x4*)(l + i) = ll;
    }
}

// fp32 (Ks x Ns) -> transposed (Ns x Ks) hi/lo bf16.
__global__ void k_tsplit(const float* __restrict__ s, u16* __restrict__ dh,
                         u16* __restrict__ dl, int Ks, int Ns)
{
    __shared__ float t[32][33];
    int tx = threadIdx.x & 31, ty = threadIdx.x >> 5;
    int kb = blockIdx.y << 5, nb_ = blockIdx.x << 5;
#pragma unroll
    for (int i = 0; i < 4; ++i)
        t[ty + 8 * i][tx] = s[(long long)(kb + ty + 8 * i) * Ns + nb_ + tx];
    __syncthreads();
#pragma unroll
    for (int i = 0; i < 4; ++i) {
        float v = t[tx][ty + 8 * i];
        long long o = (long long)(nb_ + ty + 8 * i) * Ks + kb + tx;
        u16 hh, ll; split2(v, hh, ll);
        dh[o] = hh; dl[o] = ll;
    }
}

// Per-head W transpose-split (fallback): z selects WQ/WK/WV; dst += z*E*E.
__global__ void k_tsplit3(const float* __restrict__ s0, const float* __restrict__ s1,
                          const float* __restrict__ s2,
                          u16* __restrict__ dh, u16* __restrict__ dl)
{
    const int E = 768; const long long EE = (long long)E * E;
    const float* s = (blockIdx.z == 0) ? s0 : (blockIdx.z == 1) ? s1 : s2;
    u16* h = dh + blockIdx.z * EE;
    u16* l = dl + blockIdx.z * EE;
    __shared__ float t[32][33];
    int tx = threadIdx.x & 31, ty = threadIdx.x >> 5;
    int kb = blockIdx.y << 5, nb_ = blockIdx.x << 5;
#pragma unroll
    for (int i = 0; i < 4; ++i)
        t[ty + 8 * i][tx] = s[(long long)(kb + ty + 8 * i) * E + nb_ + tx];
    __syncthreads();
#pragma unroll
    for (int i = 0; i < 4; ++i) {
        float v = t[tx][ty + 8 * i];
        long long o = (long long)(nb_ + ty + 8 * i) * E + kb + tx;
        u16 hh, ll; split2(v, hh, ll);
        h[o] = hh; l[o] = ll;
    }
}

// All-heads W transpose-split (cold path): z = h*3 + w; one launch.
__global__ void k_tsplitA(const float* __restrict__ WQ, const float* __restrict__ WK,
                          const float* __restrict__ WV,
                          u16* __restrict__ dh, u16* __restrict__ dl)
{
    const int E = 768; const long long EE = (long long)E * E;
    int hz = blockIdx.z, hh_ = hz / 3, w = hz % 3;
    const float* s = ((w == 0) ? WQ : (w == 1) ? WK : WV) + (long long)hh_ * EE;
    u16* h = dh + (long long)hz * EE;
    u16* l = dl + (long long)hz * EE;
    __shared__ float t[32][33];
    int tx = threadIdx.x & 31, ty = threadIdx.x >> 5;
    int kb = blockIdx.y << 5, nb_ = blockIdx.x << 5;
#pragma unroll
    for (int i = 0; i < 4; ++i)
        t[ty + 8 * i][tx] = s[(long long)(kb + ty + 8 * i) * E + nb_ + tx];
    __syncthreads();
#pragma unroll
    for (int i = 0; i < 4; ++i) {
        float v = t[tx][ty + 8 * i];
        long long o = (long long)(nb_ + ty + 8 * i) * E + kb + tx;
        u16 hh, ll; split2(v, hh, ll);
        h[o] = hh; l[o] = ll;
    }
}

// Normalize S in place; reduces the RC per-column partials inline. [r14]
__global__ __launch_bounds__(256)
void sm_norm(u16* __restrict__ Sh, u16* __restrict__ Sl,
             const float2* __restrict__ part, int T, float scale)
{
    const int lane = threadIdx.x & 63, seg = threadIdx.x >> 6;
    const int j0 = blockIdx.x * 256 + lane * 4;
    const long long base = (long long)blockIdx.z * T * T;
    const int rpc = T / RC, rps = rpc / 4;
    const int r0 = blockIdx.y * rpc + seg * rps;
    float mt[4], inv[4];
#pragma unroll
    for (int c = 0; c < 4; ++c) {
        float m = -3.4e38f, s = 0.f;
#pragma unroll
        for (int q = 0; q < RC; ++q) {
            float2 p = part[((long long)blockIdx.z * RC + q) * T + j0 + c];
            float mn = fmaxf(m, p.x);
            s = s * __expf(m - mn) + p.y * __expf(p.x - mn);
            m = mn;
        }
        mt[c] = m; inv[c] = 1.f / s;
    }
    for (int r = 0; r < rps; ++r) {
        long long o = base + (long long)(r0 + r) * T + j0;
        u16x4 vh = *(const u16x4*)(Sh + o);
        u16x4 vl = *(const u16x4*)(Sl + o);
        u16x4 oh, ol;
#pragma unroll
        for (int c = 0; c < 4; ++c) {
            float v = (bf2f(vh[c]) + bf2f(vl[c])) * scale;
            float p = __expf(v - mt[c]) * inv[c];
            u16 hh, ll; split2(p, hh, ll);
            oh[c] = hh; ol[c] = ll;
        }
        *(u16x4*)(Sh + o) = oh;
        *(u16x4*)(Sl + o) = ol;
    }
}

extern "C" void kernel_launch(void* const* d_in, const int* in_sizes, int n_in,
                              void* d_out, int out_size, void* d_ws, size_t ws_size,
                              hipStream_t stream)
{
    const float* x  = (const float*)d_in[0];   // (B,T,E)
    const float* WQ = (const float*)d_in[1];   // (H,E,E)
    const float* WK = (const float*)d_in[2];
    const float* WV = (const float*)d_in[3];
    const float* WO = (const float*)d_in[4];   // (H*E, E)
    float* out = (float*)d_out;                // (B,T,E)

    const int B = 8, T = 1024, E = 768, H = 12;
    const long long TE = (long long)T * E;     // 786432
    const long long TT = (long long)T * T;     // 1048576
    const long long HE = (long long)H * E;     // 9216
    const long long EE = (long long)E * E;

    // ---- fixed workspace (r14 layout) ----
    char* p = (char*)d_ws;
    u16* Xh   = (u16*)p; p += (size_t)B * TE * 2;
    u16* Xl   = (u16*)p; p += (size_t)B * TE * 2;
    u16* WOth = (u16*)p; p += (size_t)E * HE * 2;
    u16* WOtl = (u16*)p; p += (size_t)E * HE * 2;
    u16* zp   = (u16*)p; p += 4096;
    float2* part = (float2*)p; p += (size_t)B * RC * T * sizeof(float2); // 1 MB
    size_t used0 = (size_t)(p - (char*)d_ws);

    const size_t slice = (size_t)(6 * TE + 2 * TT) * 2;  // Q,K,V,S hi/lo: 13.6 MB
    const size_t zsl   = (size_t)12 * TE * 4;            // Zall/batch: 37.7 MB
    const size_t wt12  = (size_t)36 * EE * 2 * 2;        // 85 MB
    const size_t wt1   = (size_t)3 * EE * 2 * 2;         // 7 MB

    long long avail = (long long)ws_size - (long long)used0;

    const bool tierA = avail >= (long long)(wt12 + 8 * (slice + zsl));
    const bool wtAll = tierA || avail >= (long long)(wt12 + 8 * slice);

    long long wsliceF = avail - (long long)(wtAll ? wt12 : wt1);
    int NC = (int)(wsliceF / (long long)slice);
    if (NC < 1) NC = 1;
    if (NC > B) NC = B;

    u16* Wth = (u16*)p;  u16* Wtl;
    if (wtAll) { Wtl = Wth + (size_t)36 * EE; p += wt12; }
    else       { Wtl = Wth + (size_t)3 * EE;  p += wt1;  }
    u16* Qh = (u16*)p; p += (size_t)NC * TE * 2;
    u16* Ql = (u16*)p; p += (size_t)NC * TE * 2;
    u16* Kh = (u16*)p; p += (size_t)NC * TE * 2;
    u16* Kl = (u16*)p; p += (size_t)NC * TE * 2;
    u16* Vh = (u16*)p; p += (size_t)NC * TE * 2;
    u16* Vl = (u16*)p; p += (size_t)NC * TE * 2;
    u16* Sh = (u16*)p; p += (size_t)NC * TT * 2;
    u16* Sl = (u16*)p; p += (size_t)NC * TT * 2;
    u16* Zallh = (u16*)p; if (tierA) p += (size_t)8 * 12 * TE * 2;
    u16* Zalll = (u16*)p;
    u16* Zh = Qh;   // alias: Q dead after scores GEMM
    u16* Zl = Ql;

    hipMemsetAsync(out, 0, (size_t)B * TE * sizeof(float), stream);
    hipMemsetAsync(zp, 0, 4096, stream);

    dim3 blk(256);

    // One-time operand splits.
    k_split<<<2048, blk, 0, stream>>>(x, Xh, Xl, (long long)B * TE);
    k_tsplit<<<dim3(E / 32, (int)HE / 32), blk, 0, stream>>>(WO, WOth, WOtl, (int)HE, E);
    if (wtAll)
        k_tsplitA<<<dim3(24, 24, 36), blk, 0, stream>>>(WQ, WK, WV, Wth, Wtl);

    // h outer, batch-chunks inner (r8 structure).
    for (int h = 0; h < H; ++h) {
        const int i_lo = (int)(((long long)h * TE) / HE);
        const long long aShift = (long long)i_lo * HE - (long long)h * TE;

        const u16* wh; const u16* wl;
        if (wtAll) { wh = Wth + (size_t)h * 3 * EE; wl = Wtl + (size_t)h * 3 * EE; }
        else {
            k_tsplit3<<<dim3(24, 24, 3), blk, 0, stream>>>(
                WQ + (size_t)h * EE, WK + (size_t)h * EE, WV + (size_t)h * EE,
                Wth, Wtl);
            wh = Wth; wl = Wtl;
        }

        for (int b0 = 0; b0 < B; b0 += NC) {
            const int nb = (B - b0 < NC) ? (B - b0) : NC;

            // Q/K/V projections: (nb*T x 768) @ (768 x 768), XCD-aware remap.
            g_qkv<<<dim3(18, nb * T / 128), blk, 0, stream>>>(
                Xh + (size_t)b0 * TE, Xl + (size_t)b0 * TE, wh, wl,
                Qh, Ql, Kh, Kl, Vh, Vl);

            // Scores + fused softmax partials: Q @ K-flat (768,1024), ldb=T.
            g_sc<<<dim3(8, 8, nb), blk, 0, stream>>>(
                Qh, Ql, Kh, Kl, Sh, Sl, part,
                768, 768, 1024, 1024, TE, TE, TT, 0.03125f);

            // Normalize (reduces RC partials inline).
            sm_norm<<<dim3(T / 256, RC, nb), blk, 0, stream>>>(
                Sh, Sl, part, T, 0.03125f);

            if (tierA) {
                g_km<<<dim3(6, 8, nb), blk, 0, stream>>>(
                    Sh, Sl, Vh, Vl,
                    Zallh + (size_t)(b0 * 12 + h) * TE,
                    Zalll + (size_t)(b0 * 12 + h) * TE,
                    1024, 1024, 768, 768, TT, TE, 12 * TE);
            } else {
                g_km<<<dim3(6, 8, nb), blk, 0, stream>>>(
                    Sh, Sl, Vh, Vl, Zh, Zl, 1024, 1024, 768, 768, TT, TE, TE);
                g_fin<<<dim3(6, 12, nb), blk, 0, stream>>>(
                    Zh, Zl, WOth, WOtl,
                    out + (size_t)b0 * TE + (size_t)i_lo * E, zp,
                    aShift, T - i_lo, 12);
            }
        }
    }

    if (tierA) {
        g_out<<<dim3(6, 8 * 4, 8), blk, 0, stream>>>(
            Zallh, Zalll, WOth, WOtl, out, 4);
    }
}